// Round 6
// baseline (600.949 us; speedup 1.0000x reference)
//
#include <hip/hip_runtime.h>

// SimpleConcatAttention on MI355X — round 6: global_load_lds staging.
// Round-5 post-mortem: phase 2 at 150 µs, MfmaUtil 28% / VALUBusy 10% — >60%
// stall from reg-round-trip staging (load->wait->ds_write). Per m151/m193,
// global_load_lds width=16 is worth +35..67% on exactly this structure, and
// the compiler never emits it on its own.
// Round 6: all hot GEMMs stage via __builtin_amdgcn_global_load_lds(16B).
// LDS dest must be linear (wave-uniform base + lane*16), so the pad-40 layout
// is replaced by a 16B-chunk bijection L(row,j) applied to BOTH the global
// source address (pre-swizzle) and the ds_read offsets (rule 21):
//   L(row,j) = (row&3) | (((j ^ (row>>2)) & 3) << 2) | ((row>>2) << 4)
// For fixed j, L mod 8 hits each residue exactly 2x over 16 aligned rows ->
// 2-way bank aliasing on frag ds_read_b64 (free, m136). Zero ds_writes.
// Pipeline (unchanged): split key/q/W -> transpose W -> qW GEMM -> S GEMM ->
// key transpose -> softmax (dual write) -> out GEMM.  Fallback: round-1 path.

typedef float f32x4 __attribute__((ext_vector_type(4)));
typedef short bf16x8 __attribute__((ext_vector_type(8)));
typedef short s16x4 __attribute__((ext_vector_type(4)));
typedef unsigned short u16;
typedef unsigned short u16x8 __attribute__((ext_vector_type(8)));

// f32 -> bf16 (RNE) bit-twiddle (compiler-visible; proven), exact expand.
__device__ __forceinline__ u16 f2bf(float f) {
    unsigned int u = __float_as_uint(f);
    return (u16)((u + 0x7fffu + ((u >> 16) & 1u)) >> 16);
}
__device__ __forceinline__ float bf2f(u16 h) {
    return __uint_as_float(((unsigned int)h) << 16);
}

// Load 8 bf16 (two 8B halves) from LDS at two precomputed u16 offsets.
__device__ __forceinline__ bf16x8 ld2(const u16* p, int off1, int off2) {
    s16x4 a = *(const s16x4*)(p + off1);
    s16x4 b = *(const s16x4*)(p + off2);
    bf16x8 r = {a[0], a[1], a[2], a[3], b[0], b[1], b[2], b[3]};
    return r;
}

// Async 16B global -> LDS (direct, no VGPR round-trip). Dest is written at
// (wave-uniform lds ptr) + lane*16 by hardware.
__device__ __forceinline__ void gload16(const u16* g, u16* l) {
    __builtin_amdgcn_global_load_lds(
        (const __attribute__((address_space(1))) unsigned int*)g,
        (__attribute__((address_space(3))) unsigned int*)l,
        16, 0, 0);
}

// 16B-chunk layout bijection for a [rows][32] bf16 LDS tile (4 chunks/row).
// Chunk (row, j) lives at linear chunk index L; staging computes the inverse.
__device__ __forceinline__ int Lchunk(int row, int j) {
    return (row & 3) | ((((j ^ (row >> 2)) & 3)) << 2) | ((row >> 2) << 4);
}
// u16 offset of element (row, k), k in [0,32).
__device__ __forceinline__ int swzoff(int row, int k) {
    return (Lchunk(row, (k >> 3) & 3) << 3) + (k & 7);
}

// ===========================================================================
// Round-1 fused-conversion GEMM — fallback path only (ws too small).
// ===========================================================================
#define CSTR 36
__device__ __forceinline__ int swzc(int row, int k) {
    return row * CSTR + (k ^ (((row >> 2) & 7) << 2));
}
__device__ __forceinline__ bf16x8 ld_fragc(const u16* plane, int row, int kg) {
    return ld2(plane, swzc(row, kg), swzc(row, kg + 16));
}

template<bool BT, bool SPLIT>
__global__ __launch_bounds__(256, 2) void gemm_f32conv(
    const float* __restrict__ A, const float* __restrict__ B,
    float* __restrict__ C,
    int Kd, int lda, int ldb, int ldc,
    long sA, long sB, long sC, float scale)
{
    constexpr int PLANES = SPLIT ? 2 : 1;
    __shared__ u16 As[PLANES][128 * CSTR];
    __shared__ u16 Bs[PLANES][128 * CSTR];

    const int tid  = threadIdx.x;
    const int lane = tid & 63;
    const int wave = tid >> 6;
    const int wm = (wave >> 1) * 64, wn = (wave & 1) * 64;
    const int lr = lane & 15, kg = (lane >> 4) * 4;

    const int m0 = blockIdx.y * 128, n0 = blockIdx.x * 128;
    const float* Ag = A + (long)blockIdx.z * sA + (long)m0 * lda;
    const float* Bg = B + (long)blockIdx.z * sB + (BT ? (long)n0 * ldb : (long)n0);

    f32x4 acc[4][4] = {};

    for (int k0 = 0; k0 < Kd; k0 += 32) {
        __syncthreads();
#pragma unroll
        for (int it = 0; it < 4; it++) {
            const int idx = tid + it * 256;
            const int row = idx >> 3, kc = (idx & 7) * 4;
            f32x4 v = *(const f32x4*)(Ag + (long)row * lda + k0 + kc);
            ushort4 h;
            h.x = f2bf(v[0]); h.y = f2bf(v[1]); h.z = f2bf(v[2]); h.w = f2bf(v[3]);
            *(ushort4*)&As[0][swzc(row, kc)] = h;
            if constexpr (SPLIT) {
                ushort4 l;
                l.x = f2bf(v[0] - bf2f(h.x)); l.y = f2bf(v[1] - bf2f(h.y));
                l.z = f2bf(v[2] - bf2f(h.z)); l.w = f2bf(v[3] - bf2f(h.w));
                *(ushort4*)&As[1][swzc(row, kc)] = l;
            }
        }
        if constexpr (BT) {
#pragma unroll
            for (int it = 0; it < 4; it++) {
                const int idx = tid + it * 256;
                const int row = idx >> 3, kc = (idx & 7) * 4;
                f32x4 v = *(const f32x4*)(Bg + (long)row * ldb + k0 + kc);
                ushort4 h;
                h.x = f2bf(v[0]); h.y = f2bf(v[1]); h.z = f2bf(v[2]); h.w = f2bf(v[3]);
                *(ushort4*)&Bs[0][swzc(row, kc)] = h;
                if constexpr (SPLIT) {
                    ushort4 l;
                    l.x = f2bf(v[0] - bf2f(h.x)); l.y = f2bf(v[1] - bf2f(h.y));
                    l.z = f2bf(v[2] - bf2f(h.z)); l.w = f2bf(v[3] - bf2f(h.w));
                    *(ushort4*)&Bs[1][swzc(row, kc)] = l;
                }
            }
        } else {
#pragma unroll
            for (int it = 0; it < 2; it++) {
                const int idx = tid + it * 256;
                const int kk = (idx >> 5) * 2;
                const int nc = (idx & 31) * 4;
                f32x4 v0 = *(const f32x4*)(Bg + (long)(k0 + kk) * ldb + nc);
                f32x4 v1 = *(const f32x4*)(Bg + (long)(k0 + kk + 1) * ldb + nc);
#pragma unroll
                for (int e = 0; e < 4; e++) {
                    const u16 h0 = f2bf(v0[e]), h1 = f2bf(v1[e]);
                    *(unsigned*)&Bs[0][swzc(nc + e, kk)] =
                        (unsigned)h0 | ((unsigned)h1 << 16);
                    if constexpr (SPLIT) {
                        const u16 l0 = f2bf(v0[e] - bf2f(h0));
                        const u16 l1 = f2bf(v1[e] - bf2f(h1));
                        *(unsigned*)&Bs[1][swzc(nc + e, kk)] =
                            (unsigned)l0 | ((unsigned)l1 << 16);
                    }
                }
            }
        }
        __syncthreads();

        bf16x8 ah[4], bh[4], al[4], bl[4];
#pragma unroll
        for (int i = 0; i < 4; i++) {
            ah[i] = ld_fragc(&As[0][0], wm + i * 16 + lr, kg);
            if constexpr (SPLIT) al[i] = ld_fragc(&As[1][0], wm + i * 16 + lr, kg);
        }
#pragma unroll
        for (int j = 0; j < 4; j++) {
            bh[j] = ld_fragc(&Bs[0][0], wn + j * 16 + lr, kg);
            if constexpr (SPLIT) bl[j] = ld_fragc(&Bs[1][0], wn + j * 16 + lr, kg);
        }
#pragma unroll
        for (int i = 0; i < 4; i++)
#pragma unroll
            for (int j = 0; j < 4; j++) {
                acc[i][j] = __builtin_amdgcn_mfma_f32_16x16x32_bf16(
                    ah[i], bh[j], acc[i][j], 0, 0, 0);
                if constexpr (SPLIT) {
                    acc[i][j] = __builtin_amdgcn_mfma_f32_16x16x32_bf16(
                        ah[i], bl[j], acc[i][j], 0, 0, 0);
                    acc[i][j] = __builtin_amdgcn_mfma_f32_16x16x32_bf16(
                        al[i], bh[j], acc[i][j], 0, 0, 0);
                }
            }
    }

    float* Cg = C + (long)blockIdx.z * sC + (long)(m0 + wm) * ldc + n0 + wn;
    const int rbase = (lane >> 4) * 4;
#pragma unroll
    for (int i = 0; i < 4; i++)
#pragma unroll
        for (int r = 0; r < 4; r++) {
            float* cp = Cg + (long)(i * 16 + rbase + r) * ldc + lr;
#pragma unroll
            for (int j = 0; j < 4; j++)
                cp[j * 16] = acc[i][j][r] * scale;
        }
}

// ===========================================================================
// Elementwise split: src f32 -> hi/lo bf16 planes. n4 = element count / 4.
// ===========================================================================
__global__ __launch_bounds__(256) void split_f32(
    const float* __restrict__ src, u16* __restrict__ hi, u16* __restrict__ lo,
    long n4)
{
    const long stride = (long)gridDim.x * 256;
    for (long i = (long)blockIdx.x * 256 + threadIdx.x; i < n4; i += stride) {
        f32x4 v = *(const f32x4*)(src + i * 4);
        ushort4 h, l;
        h.x = f2bf(v[0]); h.y = f2bf(v[1]); h.z = f2bf(v[2]); h.w = f2bf(v[3]);
        l.x = f2bf(v[0] - bf2f(h.x)); l.y = f2bf(v[1] - bf2f(h.y));
        l.z = f2bf(v[2] - bf2f(h.z)); l.w = f2bf(v[3] - bf2f(h.w));
        *(ushort4*)(hi + i * 4) = h;
        *(ushort4*)(lo + i * 4) = l;
    }
}

// ===========================================================================
// Tiled bf16 transpose: in [Z][R][C] -> out [Z][C][R]. R,C multiples of 64.
// ===========================================================================
__global__ __launch_bounds__(256) void transpose_bf16(
    const u16* __restrict__ in, u16* __restrict__ out, int R, int C)
{
    __shared__ u16 T[64 * 72];                  // stride 72 u16 (16B-align rows)
    const int tid = threadIdx.x;
    const int c0 = blockIdx.x * 64, r0 = blockIdx.y * 64;
    const long zoff = (long)blockIdx.z * R * C;
    const u16* src = in + zoff + (long)r0 * C + c0;
#pragma unroll
    for (int it = 0; it < 2; it++) {
        const int r = it * 32 + (tid >> 3), c = (tid & 7) * 8;
        u16x8 v = *(const u16x8*)(src + (long)r * C + c);
#pragma unroll
        for (int j = 0; j < 8; j++) T[(c + j) * 72 + r] = v[j];
    }
    __syncthreads();
    u16* dst = out + zoff + (long)c0 * R + r0;
#pragma unroll
    for (int it = 0; it < 2; it++) {
        const int c = it * 32 + (tid >> 3), r = (tid & 7) * 8;
        *(u16x8*)(dst + (long)c * R + r) = *(const u16x8*)&T[c * 72 + r];
    }
}

// ===========================================================================
// bf16-input MFMA GEMM, both operands k-contiguous, global_load_lds staging.
// A: [M][lda] bf16, B: [N][ldb] bf16. Tile 128x128, BK=32, 4 waves (64x64).
// LDS: linear [128*32] per plane, 16B-chunk bijection L (see top).
// SPLIT: hi/lo planes + 3-MFMA emulation; else hi-only, 1 MFMA.
// ===========================================================================
template<bool SPLIT>
__global__ __launch_bounds__(256, 3) void gemm_bf16(
    const u16* __restrict__ Ah, const u16* __restrict__ Al,
    const u16* __restrict__ Bh, const u16* __restrict__ Bl,
    float* __restrict__ C,
    int Kd, int lda, int ldb, int ldc,
    long sA, long sB, long sC, float scale)
{
    constexpr int PL = SPLIT ? 2 : 1;
    __shared__ u16 As[PL][128 * 32];
    __shared__ u16 Bs[PL][128 * 32];

    const int tid  = threadIdx.x;
    const int lane = tid & 63;
    const int wave = tid >> 6;
    const int wm = (wave >> 1) * 64, wn = (wave & 1) * 64;
    const int lr = lane & 15, kg = (lane >> 4) * 4;

    const int m0 = blockIdx.y * 128, n0 = blockIdx.x * 128;
    const u16* Ag[PL];
    const u16* Bg[PL];
    Ag[0] = Ah + (long)blockIdx.z * sA + (long)m0 * lda;
    Bg[0] = Bh + (long)blockIdx.z * sB + (long)n0 * ldb;
    if constexpr (SPLIT) {
        Ag[1] = Al + (long)blockIdx.z * sA + (long)m0 * lda;
        Bg[1] = Bl + (long)blockIdx.z * sB + (long)n0 * ldb;
    }

    // Per-thread staging geometry (constant across K-steps): this thread
    // fills LDS chunk c = it*256 + tid; inverse of L gives the global chunk.
    int srow[2], scol[2];
#pragma unroll
    for (int it = 0; it < 2; it++) {
        const int c = it * 256 + tid;
        const int q = c >> 4, rl = c & 3, jx = (c >> 2) & 3;
        srow[it] = (q << 2) | rl;
        scol[it] = ((jx ^ q) & 3) << 3;          // u16 col of the 16B chunk
    }
    const int ldsbase0 = (tid & ~63) << 3;       // wave-uniform, u16 units
    const int ldsbase1 = (256 << 3) + ldsbase0;

    f32x4 acc[4][4] = {};

    for (int k0 = 0; k0 < Kd; k0 += 32) {
        __syncthreads();
        // ---- async stage: 16B per lane per plane per half (no VGPR trip) ----
#pragma unroll
        for (int p = 0; p < PL; p++) {
            gload16(Ag[p] + (long)srow[0] * lda + k0 + scol[0], &As[p][ldsbase0]);
            gload16(Ag[p] + (long)srow[1] * lda + k0 + scol[1], &As[p][ldsbase1]);
            gload16(Bg[p] + (long)srow[0] * ldb + k0 + scol[0], &Bs[p][ldsbase0]);
            gload16(Bg[p] + (long)srow[1] * ldb + k0 + scol[1], &Bs[p][ldsbase1]);
        }
        __syncthreads();   // compiler drains vmcnt(0) before s_barrier

        // ---- fragment loads (swizzled offsets; 2-way bank = free) ----
        bf16x8 af[PL][4], bf[PL][4];
#pragma unroll
        for (int i = 0; i < 4; i++) {
            const int r = wm + i * 16 + lr;
#pragma unroll
            for (int p = 0; p < PL; p++)
                af[p][i] = ld2(&As[p][0], swzoff(r, kg), swzoff(r, kg + 16));
        }
#pragma unroll
        for (int j = 0; j < 4; j++) {
            const int r = wn + j * 16 + lr;
#pragma unroll
            for (int p = 0; p < PL; p++)
                bf[p][j] = ld2(&Bs[p][0], swzoff(r, kg), swzoff(r, kg + 16));
        }

        // ---- MFMA ----
#pragma unroll
        for (int i = 0; i < 4; i++)
#pragma unroll
            for (int j = 0; j < 4; j++) {
                acc[i][j] = __builtin_amdgcn_mfma_f32_16x16x32_bf16(
                    af[0][i], bf[0][j], acc[i][j], 0, 0, 0);
                if constexpr (SPLIT) {
                    acc[i][j] = __builtin_amdgcn_mfma_f32_16x16x32_bf16(
                        af[0][i], bf[1][j], acc[i][j], 0, 0, 0);
                    acc[i][j] = __builtin_amdgcn_mfma_f32_16x16x32_bf16(
                        af[1][i], bf[0][j], acc[i][j], 0, 0, 0);
                }
            }
    }

    // ---- epilogue: C/D layout col=lane&15, row=(lane>>4)*4+reg ----
    float* Cg = C + (long)blockIdx.z * sC + (long)(m0 + wm) * ldc + n0 + wn;
    const int rbase = (lane >> 4) * 4;
#pragma unroll
    for (int i = 0; i < 4; i++)
#pragma unroll
        for (int r = 0; r < 4; r++) {
            float* cp = Cg + (long)(i * 16 + rbase + r) * ldc + lr;
#pragma unroll
            for (int j = 0; j < 4; j++)
                cp[j * 16] = acc[i][j][r] * scale;
        }
}

// ===========================================================================
// Phase-1 kernel: qW = (query @ W)/32, split bf16 in, hi/lo bf16 OUT.
// M=512, N=1024, K=1024, B = W^T planes [n][k]. Tile 64x64, 4 waves (32x32),
// 128 blocks; global_load_lds staging, same L bijection (64-row tiles).
// ===========================================================================
__global__ __launch_bounds__(256, 2) void gemm_qw(
    const u16* __restrict__ qh, const u16* __restrict__ ql,
    const u16* __restrict__ WhT, const u16* __restrict__ WlT,
    u16* __restrict__ qWh, u16* __restrict__ qWl)
{
    __shared__ u16 As[2][64 * 32];
    __shared__ u16 Bs[2][64 * 32];

    const int tid  = threadIdx.x;
    const int lane = tid & 63;
    const int wave = tid >> 6;
    const int wm = (wave >> 1) * 32, wn = (wave & 1) * 32;
    const int lr = lane & 15, kg = (lane >> 4) * 4;
    const int m0 = blockIdx.y * 64, n0 = blockIdx.x * 64;

    const u16* Ag[2] = { qh + (long)m0 * 1024, ql + (long)m0 * 1024 };
    const u16* Bg[2] = { WhT + (long)n0 * 1024, WlT + (long)n0 * 1024 };

    // one 16B chunk per thread per plane: c = tid (256 chunks = 64 rows x 4)
    const int q = tid >> 4, rl = tid & 3, jx = (tid >> 2) & 3;
    const int srow = (q << 2) | rl;
    const int scol = ((jx ^ q) & 3) << 3;
    const int ldsbase = (tid & ~63) << 3;        // wave-uniform

    f32x4 acc[2][2] = {};

    for (int k0 = 0; k0 < 1024; k0 += 32) {
        __syncthreads();
#pragma unroll
        for (int p = 0; p < 2; p++) {
            gload16(Ag[p] + (long)srow * 1024 + k0 + scol, &As[p][ldsbase]);
            gload16(Bg[p] + (long)srow * 1024 + k0 + scol, &Bs[p][ldsbase]);
        }
        __syncthreads();

        bf16x8 af[2][2], bfr[2][2];
#pragma unroll
        for (int i = 0; i < 2; i++) {
            const int r = wm + i * 16 + lr;
#pragma unroll
            for (int p = 0; p < 2; p++)
                af[p][i] = ld2(&As[p][0], swzoff(r, kg), swzoff(r, kg + 16));
        }
#pragma unroll
        for (int j = 0; j < 2; j++) {
            const int r = wn + j * 16 + lr;
#pragma unroll
            for (int p = 0; p < 2; p++)
                bfr[p][j] = ld2(&Bs[p][0], swzoff(r, kg), swzoff(r, kg + 16));
        }
#pragma unroll
        for (int i = 0; i < 2; i++)
#pragma unroll
            for (int j = 0; j < 2; j++) {
                acc[i][j] = __builtin_amdgcn_mfma_f32_16x16x32_bf16(
                    af[0][i], bfr[0][j], acc[i][j], 0, 0, 0);
                acc[i][j] = __builtin_amdgcn_mfma_f32_16x16x32_bf16(
                    af[0][i], bfr[1][j], acc[i][j], 0, 0, 0);
                acc[i][j] = __builtin_amdgcn_mfma_f32_16x16x32_bf16(
                    af[1][i], bfr[0][j], acc[i][j], 0, 0, 0);
            }
    }

    // Epilogue: scale by 1/32 and split-write hi/lo bf16 planes directly.
    const int rbase = (lane >> 4) * 4;
#pragma unroll
    for (int i = 0; i < 2; i++)
#pragma unroll
        for (int r = 0; r < 4; r++) {
            const long ro = (long)(m0 + wm + i * 16 + rbase + r) * 1024 + n0 + wn + lr;
#pragma unroll
            for (int j = 0; j < 2; j++) {
                const float v = acc[i][j][r] * (1.f / 32.f);
                const u16 h = f2bf(v);
                qWh[ro + j * 16] = h;
                qWl[ro + j * 16] = f2bf(v - bf2f(h));
            }
        }
}

// ===========================================================================
// Masked softmax over rows of 2048, in place on f32 scores; optionally also
// writes a bf16 copy (phase-4 A operand). One block per row.
// ===========================================================================
__global__ __launch_bounds__(256) void softmax_rows(
    float* __restrict__ att, const int* __restrict__ mask, u16* __restrict__ abf)
{
    const int  row  = blockIdx.x;                    // b*512 + k
    const int  tid  = threadIdx.x;
    const long base = (long)row * 2048 + tid * 8;

    f32x4 s0 = *(const f32x4*)(att + base);
    f32x4 s1 = *(const f32x4*)(att + base + 4);
    int4  mv0 = *(const int4*)(mask + base);
    int4  mv1 = *(const int4*)(mask + base + 4);
    const int mk[8] = {mv0.x, mv0.y, mv0.z, mv0.w, mv1.x, mv1.y, mv1.z, mv1.w};

    float x[8] = {s0[0], s0[1], s0[2], s0[3], s1[0], s1[1], s1[2], s1[3]};
#pragma unroll
    for (int j = 0; j < 8; j++) x[j] = mk[j] ? x[j] : -INFINITY;

    float mx = x[0];
#pragma unroll
    for (int j = 1; j < 8; j++) mx = fmaxf(mx, x[j]);
#pragma unroll
    for (int off = 32; off > 0; off >>= 1) mx = fmaxf(mx, __shfl_down(mx, off));

    __shared__ float red[8];
    const int wave = tid >> 6, lane = tid & 63;
    if (lane == 0) red[wave] = mx;
    __syncthreads();
    mx = fmaxf(fmaxf(red[0], red[1]), fmaxf(red[2], red[3]));

    if (mx == -INFINITY) {                           // all-masked row: zeros, not NaN
        f32x4 z = {0.f, 0.f, 0.f, 0.f};
        *(f32x4*)(att + base) = z;
        *(f32x4*)(att + base + 4) = z;
        if (abf) {
            u16x8 zb = {0, 0, 0, 0, 0, 0, 0, 0};
            *(u16x8*)(abf + base) = zb;
        }
        return;
    }

    float e[8], s = 0.f;
#pragma unroll
    for (int j = 0; j < 8; j++) { e[j] = __expf(x[j] - mx); s += e[j]; }
#pragma unroll
    for (int off = 32; off > 0; off >>= 1) s += __shfl_down(s, off);
    if (lane == 0) red[4 + wave] = s;
    __syncthreads();
    s = red[4] + red[5] + red[6] + red[7];

    const float inv = 1.f / s;
    float o[8];
#pragma unroll
    for (int j = 0; j < 8; j++) o[j] = e[j] * inv;
    f32x4 o0 = {o[0], o[1], o[2], o[3]}, o1 = {o[4], o[5], o[6], o[7]};
    *(f32x4*)(att + base) = o0;
    *(f32x4*)(att + base + 4) = o1;
    if (abf) {
        u16x8 pb;
#pragma unroll
        for (int j = 0; j < 8; j++) pb[j] = f2bf(o[j]);
        *(u16x8*)(abf + base) = pb;
    }
}

// ===========================================================================
extern "C" void kernel_launch(void* const* d_in, const int* in_sizes, int n_in,
                              void* d_out, int out_size, void* d_ws, size_t ws_size,
                              hipStream_t stream)
{
    const float* query = nullptr;   // 512*1024      = 524288
    const float* key   = nullptr;   // 16*2048*1024  = 33554432
    const float* W     = nullptr;   // 1024*1024     = 1048576
    const int*   mask  = nullptr;   // 16*512*2048   = 16777216
    for (int i = 0; i < n_in; i++) {
        switch (in_sizes[i]) {
            case 524288:   query = (const float*)d_in[i]; break;
            case 33554432: key   = (const float*)d_in[i]; break;
            case 1048576:  W     = (const float*)d_in[i]; break;
            case 16777216: mask  = (const int*)d_in[i];   break;
        }
    }

    float* out = (float*)d_out;                     // [16,512,1024] f32
    float* att = out + (long)16 * 512 * 1024;       // [16,512,2048] f32

    const long KEY_E = 16L * 2048 * 1024;           // 33,554,432
    const long ATT_E = 16L * 512 * 2048;            // 16,777,216
    const long QW_E  = 512L * 1024;                 //    524,288
    const long W_E   = 1024L * 1024;                //  1,048,576
    // ws layout: key_hi | key_lo(-> key_hT after phase 2) | att_b | qW_hi | qW_lo
    // Phase-1 scratch (q/W planes + W^T planes) aliases into att_b (dead until
    // softmax). WS_NEED identical to rounds 4/5.
    const size_t WS_NEED = (size_t)(2 * KEY_E + ATT_E + 2 * QW_E) * 2;

    if (ws_size >= WS_NEED && d_ws != nullptr) {
        u16* key_hi = (u16*)d_ws;
        u16* key_lo = key_hi + KEY_E;   // becomes key_hT after phase 2
        u16* att_b  = key_lo + KEY_E;
        u16* qW_hi  = att_b + ATT_E;
        u16* qW_lo  = qW_hi + QW_E;
        // phase-1 scratch aliased into att_b (all dead by softmax time):
        u16* q_hi   = att_b;
        u16* q_lo   = q_hi + QW_E;
        u16* W_hi   = q_lo + QW_E;
        u16* W_lo   = W_hi + W_E;
        u16* W_hiT  = W_lo + W_E;
        u16* W_loT  = W_hiT + W_E;

        // 0) split key / query / W into hi+lo bf16 planes (memory-bound)
        split_f32<<<dim3(4096), 256, 0, stream>>>(key, key_hi, key_lo, KEY_E / 4);
        split_f32<<<dim3(512),  256, 0, stream>>>(query, q_hi, q_lo, QW_E / 4);
        split_f32<<<dim3(1024), 256, 0, stream>>>(W, W_hi, W_lo, W_E / 4);

        // 0b) transpose W planes: [1024 k][1024 n] -> [1024 n][1024 k]
        transpose_bf16<<<dim3(16, 16, 1), 256, 0, stream>>>(W_hi, W_hiT, 1024, 1024);
        transpose_bf16<<<dim3(16, 16, 1), 256, 0, stream>>>(W_lo, W_loT, 1024, 1024);

        // 1) qW hi/lo = (query @ W) / 32   [512 x 1024], 128 blocks
        gemm_qw<<<dim3(16, 8, 1), 256, 0, stream>>>(
            q_hi, q_lo, W_hiT, W_loT, qW_hi, qW_lo);

        // 2) S[b] = qW @ key[b]^T    [512 x 2048], K=1024, split bf16 GEMM
        gemm_bf16<true><<<dim3(16, 4, 16), 256, 0, stream>>>(
            qW_hi, qW_lo, key_hi, key_lo, att,
            1024, 1024, 1024, 2048,
            0L, (long)2048 * 1024, (long)512 * 2048, 1.f);

        // 2b) transpose key_hi [b][2048 n][1024 d] -> key_hT [b][1024 d][2048 n]
        u16* key_hT = key_lo;
        transpose_bf16<<<dim3(16, 32, 16), 256, 0, stream>>>(
            key_hi, key_hT, 2048, 1024);

        // 3) masked softmax, dual-write f32 + bf16 (overwrites q/W scratch)
        softmax_rows<<<dim3(16 * 512), 256, 0, stream>>>(att, mask, att_b);

        // 4) out[b] = att[b] @ key[b]  [512 x 1024], K=2048, plain bf16 GEMM
        gemm_bf16<false><<<dim3(8, 4, 16), 256, 0, stream>>>(
            att_b, nullptr, key_hT, nullptr, out,
            2048, 2048, 2048, 1024,
            (long)512 * 2048, (long)1024 * 2048, (long)512 * 1024, 1.f);
    } else {
        // -------- fallback: round-1 path, no workspace --------
        float* qW = out;    // f32 scratch in out region (dead before phase 4)
        gemm_f32conv<false, true><<<dim3(8, 4, 1), 256, 0, stream>>>(
            query, W, qW, 1024, 1024, 1024, 1024, 0L, 0L, 0L, 1.f / 32.f);
        gemm_f32conv<true, true><<<dim3(16, 4, 16), 256, 0, stream>>>(
            qW, key, att, 1024, 1024, 1024, 2048,
            0L, (long)2048 * 1024, (long)512 * 2048, 1.f);
        softmax_rows<<<dim3(16 * 512), 256, 0, stream>>>(att, mask, nullptr);
        gemm_f32conv<false, false><<<dim3(8, 4, 16), 256, 0, stream>>>(
            att, key, out, 2048, 2048, 1024, 1024,
            (long)512 * 2048, (long)2048 * 1024, (long)512 * 1024, 1.f);
    }
}

// Round 7
// 541.278 us; speedup vs baseline: 1.1102x; 1.1102x over previous
//
#include <hip/hip_runtime.h>

// SimpleConcatAttention on MI355X — round 7: revert to reg-staging + T14 prefetch.
// Round-6 post-mortem: global_load_lds REGRESSED ph2 150->189 µs (MfmaUtil 28->22).
// Mechanism: gload_lds can't be hoisted across the barrier, so every K-step
// exposes full L2/L3 latency (barrier -> 8 VMEM -> vmcnt(0) -> barrier); the
// reg-staged path had let loads overlap other work. Round 7 = measured-best
// round-4 staging (pad-40, copy loops) + EXPLICIT async-STAGE split (G15/T14):
//   top of iter: barrier; ds_write regs (tile k); barrier;
//   then: issue global loads for tile k+1 (regs); frag ds_reads; 48 MFMA.
// Load latency hides under the MFMA phase; the only consumer (next ds_write)
// waits a full compute-phase later. Costs ~32 VGPR, no LDS.
// Pipeline (as round 5/6): split key/q/W -> W^T -> qW GEMM -> S GEMM ->
// key^T -> softmax (dual write) -> out GEMM (key_hT, copy-staged both sides).

typedef float f32x4 __attribute__((ext_vector_type(4)));
typedef short bf16x8 __attribute__((ext_vector_type(8)));
typedef short s16x4 __attribute__((ext_vector_type(4)));
typedef unsigned short u16;
typedef unsigned short u16x8 __attribute__((ext_vector_type(8)));

// f32 -> bf16 (RNE) bit-twiddle (compiler-visible; proven), exact expand.
__device__ __forceinline__ u16 f2bf(float f) {
    unsigned int u = __float_as_uint(f);
    return (u16)((u + 0x7fffu + ((u >> 16) & 1u)) >> 16);
}
__device__ __forceinline__ float bf2f(u16 h) {
    return __uint_as_float(((unsigned int)h) << 16);
}

// Load 8 bf16 (two 8B halves) from LDS at two precomputed u16 offsets.
__device__ __forceinline__ bf16x8 ld2(const u16* p, int off1, int off2) {
    s16x4 a = *(const s16x4*)(p + off1);
    s16x4 b = *(const s16x4*)(p + off2);
    bf16x8 r = {a[0], a[1], a[2], a[3], b[0], b[1], b[2], b[3]};
    return r;
}

// ===========================================================================
// Round-1 fused-conversion GEMM — fallback path only (ws too small).
// ===========================================================================
#define CSTR 36
__device__ __forceinline__ int swzc(int row, int k) {
    return row * CSTR + (k ^ (((row >> 2) & 7) << 2));
}
__device__ __forceinline__ bf16x8 ld_fragc(const u16* plane, int row, int kg) {
    return ld2(plane, swzc(row, kg), swzc(row, kg + 16));
}

template<bool BT, bool SPLIT>
__global__ __launch_bounds__(256, 2) void gemm_f32conv(
    const float* __restrict__ A, const float* __restrict__ B,
    float* __restrict__ C,
    int Kd, int lda, int ldb, int ldc,
    long sA, long sB, long sC, float scale)
{
    constexpr int PLANES = SPLIT ? 2 : 1;
    __shared__ u16 As[PLANES][128 * CSTR];
    __shared__ u16 Bs[PLANES][128 * CSTR];

    const int tid  = threadIdx.x;
    const int lane = tid & 63;
    const int wave = tid >> 6;
    const int wm = (wave >> 1) * 64, wn = (wave & 1) * 64;
    const int lr = lane & 15, kg = (lane >> 4) * 4;

    const int m0 = blockIdx.y * 128, n0 = blockIdx.x * 128;
    const float* Ag = A + (long)blockIdx.z * sA + (long)m0 * lda;
    const float* Bg = B + (long)blockIdx.z * sB + (BT ? (long)n0 * ldb : (long)n0);

    f32x4 acc[4][4] = {};

    for (int k0 = 0; k0 < Kd; k0 += 32) {
        __syncthreads();
#pragma unroll
        for (int it = 0; it < 4; it++) {
            const int idx = tid + it * 256;
            const int row = idx >> 3, kc = (idx & 7) * 4;
            f32x4 v = *(const f32x4*)(Ag + (long)row * lda + k0 + kc);
            ushort4 h;
            h.x = f2bf(v[0]); h.y = f2bf(v[1]); h.z = f2bf(v[2]); h.w = f2bf(v[3]);
            *(ushort4*)&As[0][swzc(row, kc)] = h;
            if constexpr (SPLIT) {
                ushort4 l;
                l.x = f2bf(v[0] - bf2f(h.x)); l.y = f2bf(v[1] - bf2f(h.y));
                l.z = f2bf(v[2] - bf2f(h.z)); l.w = f2bf(v[3] - bf2f(h.w));
                *(ushort4*)&As[1][swzc(row, kc)] = l;
            }
        }
        if constexpr (BT) {
#pragma unroll
            for (int it = 0; it < 4; it++) {
                const int idx = tid + it * 256;
                const int row = idx >> 3, kc = (idx & 7) * 4;
                f32x4 v = *(const f32x4*)(Bg + (long)row * ldb + k0 + kc);
                ushort4 h;
                h.x = f2bf(v[0]); h.y = f2bf(v[1]); h.z = f2bf(v[2]); h.w = f2bf(v[3]);
                *(ushort4*)&Bs[0][swzc(row, kc)] = h;
                if constexpr (SPLIT) {
                    ushort4 l;
                    l.x = f2bf(v[0] - bf2f(h.x)); l.y = f2bf(v[1] - bf2f(h.y));
                    l.z = f2bf(v[2] - bf2f(h.z)); l.w = f2bf(v[3] - bf2f(h.w));
                    *(ushort4*)&Bs[1][swzc(row, kc)] = l;
                }
            }
        } else {
#pragma unroll
            for (int it = 0; it < 2; it++) {
                const int idx = tid + it * 256;
                const int kk = (idx >> 5) * 2;
                const int nc = (idx & 31) * 4;
                f32x4 v0 = *(const f32x4*)(Bg + (long)(k0 + kk) * ldb + nc);
                f32x4 v1 = *(const f32x4*)(Bg + (long)(k0 + kk + 1) * ldb + nc);
#pragma unroll
                for (int e = 0; e < 4; e++) {
                    const u16 h0 = f2bf(v0[e]), h1 = f2bf(v1[e]);
                    *(unsigned*)&Bs[0][swzc(nc + e, kk)] =
                        (unsigned)h0 | ((unsigned)h1 << 16);
                    if constexpr (SPLIT) {
                        const u16 l0 = f2bf(v0[e] - bf2f(h0));
                        const u16 l1 = f2bf(v1[e] - bf2f(h1));
                        *(unsigned*)&Bs[1][swzc(nc + e, kk)] =
                            (unsigned)l0 | ((unsigned)l1 << 16);
                    }
                }
            }
        }
        __syncthreads();

        bf16x8 ah[4], bh[4], al[4], bl[4];
#pragma unroll
        for (int i = 0; i < 4; i++) {
            ah[i] = ld_fragc(&As[0][0], wm + i * 16 + lr, kg);
            if constexpr (SPLIT) al[i] = ld_fragc(&As[1][0], wm + i * 16 + lr, kg);
        }
#pragma unroll
        for (int j = 0; j < 4; j++) {
            bh[j] = ld_fragc(&Bs[0][0], wn + j * 16 + lr, kg);
            if constexpr (SPLIT) bl[j] = ld_fragc(&Bs[1][0], wn + j * 16 + lr, kg);
        }
#pragma unroll
        for (int i = 0; i < 4; i++)
#pragma unroll
            for (int j = 0; j < 4; j++) {
                acc[i][j] = __builtin_amdgcn_mfma_f32_16x16x32_bf16(
                    ah[i], bh[j], acc[i][j], 0, 0, 0);
                if constexpr (SPLIT) {
                    acc[i][j] = __builtin_amdgcn_mfma_f32_16x16x32_bf16(
                        ah[i], bl[j], acc[i][j], 0, 0, 0);
                    acc[i][j] = __builtin_amdgcn_mfma_f32_16x16x32_bf16(
                        al[i], bh[j], acc[i][j], 0, 0, 0);
                }
            }
    }

    float* Cg = C + (long)blockIdx.z * sC + (long)(m0 + wm) * ldc + n0 + wn;
    const int rbase = (lane >> 4) * 4;
#pragma unroll
    for (int i = 0; i < 4; i++)
#pragma unroll
        for (int r = 0; r < 4; r++) {
            float* cp = Cg + (long)(i * 16 + rbase + r) * ldc + lr;
#pragma unroll
            for (int j = 0; j < 4; j++)
                cp[j * 16] = acc[i][j][r] * scale;
        }
}

// ===========================================================================
// Elementwise split: src f32 -> hi/lo bf16 planes. n4 = element count / 4.
// ===========================================================================
__global__ __launch_bounds__(256) void split_f32(
    const float* __restrict__ src, u16* __restrict__ hi, u16* __restrict__ lo,
    long n4)
{
    const long stride = (long)gridDim.x * 256;
    for (long i = (long)blockIdx.x * 256 + threadIdx.x; i < n4; i += stride) {
        f32x4 v = *(const f32x4*)(src + i * 4);
        ushort4 h, l;
        h.x = f2bf(v[0]); h.y = f2bf(v[1]); h.z = f2bf(v[2]); h.w = f2bf(v[3]);
        l.x = f2bf(v[0] - bf2f(h.x)); l.y = f2bf(v[1] - bf2f(h.y));
        l.z = f2bf(v[2] - bf2f(h.z)); l.w = f2bf(v[3] - bf2f(h.w));
        *(ushort4*)(hi + i * 4) = h;
        *(ushort4*)(lo + i * 4) = l;
    }
}

// ===========================================================================
// Tiled bf16 transpose: in [Z][R][C] -> out [Z][C][R]. R,C multiples of 64.
// ===========================================================================
__global__ __launch_bounds__(256) void transpose_bf16(
    const u16* __restrict__ in, u16* __restrict__ out, int R, int C)
{
    __shared__ u16 T[64 * 72];                  // stride 72 u16 (16B-align rows)
    const int tid = threadIdx.x;
    const int c0 = blockIdx.x * 64, r0 = blockIdx.y * 64;
    const long zoff = (long)blockIdx.z * R * C;
    const u16* src = in + zoff + (long)r0 * C + c0;
#pragma unroll
    for (int it = 0; it < 2; it++) {
        const int r = it * 32 + (tid >> 3), c = (tid & 7) * 8;
        u16x8 v = *(const u16x8*)(src + (long)r * C + c);
#pragma unroll
        for (int j = 0; j < 8; j++) T[(c + j) * 72 + r] = v[j];
    }
    __syncthreads();
    u16* dst = out + zoff + (long)c0 * R + r0;
#pragma unroll
    for (int it = 0; it < 2; it++) {
        const int c = it * 32 + (tid >> 3), r = (tid & 7) * 8;
        *(u16x8*)(dst + (long)c * R + r) = *(const u16x8*)&T[c * 72 + r];
    }
}

// ===========================================================================
// bf16-input MFMA GEMM, both operands k-contiguous, reg-staged (pad-40) with
// T14 async-STAGE split: global loads for tile k+1 issue right after the
// post-stage barrier, hiding HBM/L2 latency under the MFMA phase; the only
// consumer (next iteration's ds_write) is a full compute-phase later.
// A: [M][lda] bf16, B: [N][ldb] bf16. Tile 128x128, BK=32, 4 waves (64x64).
// SPLIT: hi/lo planes + 3-MFMA emulation; else hi-only, 1 MFMA.
// ===========================================================================
#define ASTR 40
template<bool SPLIT>
__global__ __launch_bounds__(256, 3) void gemm_bf16(
    const u16* __restrict__ Ah, const u16* __restrict__ Al,
    const u16* __restrict__ Bh, const u16* __restrict__ Bl,
    float* __restrict__ C,
    int Kd, int lda, int ldb, int ldc,
    long sA, long sB, long sC, float scale)
{
    constexpr int PL = SPLIT ? 2 : 1;
    __shared__ u16 As[PL][128 * ASTR];
    __shared__ u16 Bs[PL][128 * ASTR];

    const int tid  = threadIdx.x;
    const int lane = tid & 63;
    const int wave = tid >> 6;
    const int wm = (wave >> 1) * 64, wn = (wave & 1) * 64;
    const int lr = lane & 15, kg = (lane >> 4) * 4;

    const int m0 = blockIdx.y * 128, n0 = blockIdx.x * 128;
    const u16* Ag[PL];
    const u16* Bg[PL];
    Ag[0] = Ah + (long)blockIdx.z * sA + (long)m0 * lda;
    Bg[0] = Bh + (long)blockIdx.z * sB + (long)n0 * ldb;
    if constexpr (SPLIT) {
        Ag[1] = Al + (long)blockIdx.z * sA + (long)m0 * lda;
        Bg[1] = Bl + (long)blockIdx.z * sB + (long)n0 * ldb;
    }

    // Per-thread staging coords: rows srow, srow+64; 8 bf16 at col scol.
    const int srow = tid >> 2, scol = (tid & 3) * 8;

    // Prefetch registers (static indices only — rule #20).
    u16x8 ra[PL][2], rb[PL][2];
#pragma unroll
    for (int p = 0; p < PL; p++)
#pragma unroll
        for (int it = 0; it < 2; it++) {
            ra[p][it] = *(const u16x8*)(Ag[p] + (long)(srow + it * 64) * lda + scol);
            rb[p][it] = *(const u16x8*)(Bg[p] + (long)(srow + it * 64) * ldb + scol);
        }

    f32x4 acc[4][4] = {};

    for (int k0 = 0; k0 < Kd; k0 += 32) {
        __syncthreads();
        // ---- STAGE_WRITE: regs (tile k0) -> LDS. A planes, then B planes. ----
#pragma unroll
        for (int p = 0; p < PL; p++)
#pragma unroll
            for (int it = 0; it < 2; it++)
                *(u16x8*)&As[p][(srow + it * 64) * ASTR + scol] = ra[p][it];
#pragma unroll
        for (int p = 0; p < PL; p++)
#pragma unroll
            for (int it = 0; it < 2; it++)
                *(u16x8*)&Bs[p][(srow + it * 64) * ASTR + scol] = rb[p][it];
        __syncthreads();

        // ---- STAGE_LOAD (T14): issue tile k0+32 loads before the MFMA phase ----
        if (k0 + 32 < Kd) {
            const int kn = k0 + 32;
#pragma unroll
            for (int p = 0; p < PL; p++)
#pragma unroll
                for (int it = 0; it < 2; it++) {
                    ra[p][it] = *(const u16x8*)(Ag[p] + (long)(srow + it * 64) * lda + kn + scol);
                    rb[p][it] = *(const u16x8*)(Bg[p] + (long)(srow + it * 64) * ldb + kn + scol);
                }
        }

        // ---- fragment loads ----
        bf16x8 af[PL][4], bf[PL][4];
#pragma unroll
        for (int i = 0; i < 4; i++) {
            const int r = wm + i * 16 + lr;
#pragma unroll
            for (int p = 0; p < PL; p++)
                af[p][i] = ld2(&As[p][0], r * ASTR + kg, r * ASTR + kg + 16);
        }
#pragma unroll
        for (int j = 0; j < 4; j++) {
            const int r = wn + j * 16 + lr;
#pragma unroll
            for (int p = 0; p < PL; p++)
                bf[p][j] = ld2(&Bs[p][0], r * ASTR + kg, r * ASTR + kg + 16);
        }

        // ---- MFMA ----
#pragma unroll
        for (int i = 0; i < 4; i++)
#pragma unroll
            for (int j = 0; j < 4; j++) {
                acc[i][j] = __builtin_amdgcn_mfma_f32_16x16x32_bf16(
                    af[0][i], bf[0][j], acc[i][j], 0, 0, 0);
                if constexpr (SPLIT) {
                    acc[i][j] = __builtin_amdgcn_mfma_f32_16x16x32_bf16(
                        af[0][i], bf[1][j], acc[i][j], 0, 0, 0);
                    acc[i][j] = __builtin_amdgcn_mfma_f32_16x16x32_bf16(
                        af[1][i], bf[0][j], acc[i][j], 0, 0, 0);
                }
            }
    }

    // ---- epilogue: C/D layout col=lane&15, row=(lane>>4)*4+reg ----
    float* Cg = C + (long)blockIdx.z * sC + (long)(m0 + wm) * ldc + n0 + wn;
    const int rbase = (lane >> 4) * 4;
#pragma unroll
    for (int i = 0; i < 4; i++)
#pragma unroll
        for (int r = 0; r < 4; r++) {
            float* cp = Cg + (long)(i * 16 + rbase + r) * ldc + lr;
#pragma unroll
            for (int j = 0; j < 4; j++)
                cp[j * 16] = acc[i][j][r] * scale;
        }
}

// ===========================================================================
// Phase-1 kernel: qW = (query @ W)/32, split bf16 in, hi/lo bf16 OUT.
// M=512, N=1024, K=1024, B = W^T planes [n][k]. Tile 64x64, 4 waves (32x32),
// 128 blocks; copy staging (pad-40), both operands k-contiguous.
// ===========================================================================
__global__ __launch_bounds__(256, 2) void gemm_qw(
    const u16* __restrict__ qh, const u16* __restrict__ ql,
    const u16* __restrict__ WhT, const u16* __restrict__ WlT,
    u16* __restrict__ qWh, u16* __restrict__ qWl)
{
    __shared__ u16 As[2][64 * ASTR];
    __shared__ u16 Bs[2][64 * ASTR];

    const int tid  = threadIdx.x;
    const int lane = tid & 63;
    const int wave = tid >> 6;
    const int wm = (wave >> 1) * 32, wn = (wave & 1) * 32;
    const int lr = lane & 15, kg = (lane >> 4) * 4;
    const int m0 = blockIdx.y * 64, n0 = blockIdx.x * 64;

    const u16* Ag[2] = { qh + (long)m0 * 1024, ql + (long)m0 * 1024 };
    const u16* Bg[2] = { WhT + (long)n0 * 1024, WlT + (long)n0 * 1024 };

    f32x4 acc[2][2] = {};

    for (int k0 = 0; k0 < 1024; k0 += 32) {
        __syncthreads();
        const int row = tid >> 2, kc = (tid & 3) * 8;   // 64 rows x 32 k per plane
#pragma unroll
        for (int p = 0; p < 2; p++) {
            *(u16x8*)&As[p][row * ASTR + kc] =
                *(const u16x8*)(Ag[p] + (long)row * 1024 + k0 + kc);
            *(u16x8*)&Bs[p][row * ASTR + kc] =
                *(const u16x8*)(Bg[p] + (long)row * 1024 + k0 + kc);
        }
        __syncthreads();

        bf16x8 af[2][2], bfr[2][2];
#pragma unroll
        for (int i = 0; i < 2; i++) {
            const int r = wm + i * 16 + lr;
#pragma unroll
            for (int p = 0; p < 2; p++)
                af[p][i] = ld2(&As[p][0], r * ASTR + kg, r * ASTR + kg + 16);
        }
#pragma unroll
        for (int j = 0; j < 2; j++) {
            const int r = wn + j * 16 + lr;
#pragma unroll
            for (int p = 0; p < 2; p++)
                bfr[p][j] = ld2(&Bs[p][0], r * ASTR + kg, r * ASTR + kg + 16);
        }
#pragma unroll
        for (int i = 0; i < 2; i++)
#pragma unroll
            for (int j = 0; j < 2; j++) {
                acc[i][j] = __builtin_amdgcn_mfma_f32_16x16x32_bf16(
                    af[0][i], bfr[0][j], acc[i][j], 0, 0, 0);
                acc[i][j] = __builtin_amdgcn_mfma_f32_16x16x32_bf16(
                    af[0][i], bfr[1][j], acc[i][j], 0, 0, 0);
                acc[i][j] = __builtin_amdgcn_mfma_f32_16x16x32_bf16(
                    af[1][i], bfr[0][j], acc[i][j], 0, 0, 0);
            }
    }

    // Epilogue: scale by 1/32 and split-write hi/lo bf16 planes directly.
    const int rbase = (lane >> 4) * 4;
#pragma unroll
    for (int i = 0; i < 2; i++)
#pragma unroll
        for (int r = 0; r < 4; r++) {
            const long ro = (long)(m0 + wm + i * 16 + rbase + r) * 1024 + n0 + wn + lr;
#pragma unroll
            for (int j = 0; j < 2; j++) {
                const float v = acc[i][j][r] * (1.f / 32.f);
                const u16 h = f2bf(v);
                qWh[ro + j * 16] = h;
                qWl[ro + j * 16] = f2bf(v - bf2f(h));
            }
        }
}

// ===========================================================================
// Masked softmax over rows of 2048, in place on f32 scores; optionally also
// writes a bf16 copy (phase-4 A operand). One block per row.
// ===========================================================================
__global__ __launch_bounds__(256) void softmax_rows(
    float* __restrict__ att, const int* __restrict__ mask, u16* __restrict__ abf)
{
    const int  row  = blockIdx.x;                    // b*512 + k
    const int  tid  = threadIdx.x;
    const long base = (long)row * 2048 + tid * 8;

    f32x4 s0 = *(const f32x4*)(att + base);
    f32x4 s1 = *(const f32x4*)(att + base + 4);
    int4  mv0 = *(const int4*)(mask + base);
    int4  mv1 = *(const int4*)(mask + base + 4);
    const int mk[8] = {mv0.x, mv0.y, mv0.z, mv0.w, mv1.x, mv1.y, mv1.z, mv1.w};

    float x[8] = {s0[0], s0[1], s0[2], s0[3], s1[0], s1[1], s1[2], s1[3]};
#pragma unroll
    for (int j = 0; j < 8; j++) x[j] = mk[j] ? x[j] : -INFINITY;

    float mx = x[0];
#pragma unroll
    for (int j = 1; j < 8; j++) mx = fmaxf(mx, x[j]);
#pragma unroll
    for (int off = 32; off > 0; off >>= 1) mx = fmaxf(mx, __shfl_down(mx, off));

    __shared__ float red[8];
    const int wave = tid >> 6, lane = tid & 63;
    if (lane == 0) red[wave] = mx;
    __syncthreads();
    mx = fmaxf(fmaxf(red[0], red[1]), fmaxf(red[2], red[3]));

    if (mx == -INFINITY) {                           // all-masked row: zeros, not NaN
        f32x4 z = {0.f, 0.f, 0.f, 0.f};
        *(f32x4*)(att + base) = z;
        *(f32x4*)(att + base + 4) = z;
        if (abf) {
            u16x8 zb = {0, 0, 0, 0, 0, 0, 0, 0};
            *(u16x8*)(abf + base) = zb;
        }
        return;
    }

    float e[8], s = 0.f;
#pragma unroll
    for (int j = 0; j < 8; j++) { e[j] = __expf(x[j] - mx); s += e[j]; }
#pragma unroll
    for (int off = 32; off > 0; off >>= 1) s += __shfl_down(s, off);
    if (lane == 0) red[4 + wave] = s;
    __syncthreads();
    s = red[4] + red[5] + red[6] + red[7];

    const float inv = 1.f / s;
    float o[8];
#pragma unroll
    for (int j = 0; j < 8; j++) o[j] = e[j] * inv;
    f32x4 o0 = {o[0], o[1], o[2], o[3]}, o1 = {o[4], o[5], o[6], o[7]};
    *(f32x4*)(att + base) = o0;
    *(f32x4*)(att + base + 4) = o1;
    if (abf) {
        u16x8 pb;
#pragma unroll
        for (int j = 0; j < 8; j++) pb[j] = f2bf(o[j]);
        *(u16x8*)(abf + base) = pb;
    }
}

// ===========================================================================
extern "C" void kernel_launch(void* const* d_in, const int* in_sizes, int n_in,
                              void* d_out, int out_size, void* d_ws, size_t ws_size,
                              hipStream_t stream)
{
    const float* query = nullptr;   // 512*1024      = 524288
    const float* key   = nullptr;   // 16*2048*1024  = 33554432
    const float* W     = nullptr;   // 1024*1024     = 1048576
    const int*   mask  = nullptr;   // 16*512*2048   = 16777216
    for (int i = 0; i < n_in; i++) {
        switch (in_sizes[i]) {
            case 524288:   query = (const float*)d_in[i]; break;
            case 33554432: key   = (const float*)d_in[i]; break;
            case 1048576:  W     = (const float*)d_in[i]; break;
            case 16777216: mask  = (const int*)d_in[i];   break;
        }
    }

    float* out = (float*)d_out;                     // [16,512,1024] f32
    float* att = out + (long)16 * 512 * 1024;       // [16,512,2048] f32

    const long KEY_E = 16L * 2048 * 1024;           // 33,554,432
    const long ATT_E = 16L * 512 * 2048;            // 16,777,216
    const long QW_E  = 512L * 1024;                 //    524,288
    const long W_E   = 1024L * 1024;                //  1,048,576
    // ws layout: key_hi | key_lo(-> key_hT after phase 2) | att_b | qW_hi | qW_lo
    // Phase-1 scratch (q/W planes + W^T planes) aliases into att_b (dead until
    // softmax). WS_NEED identical to rounds 4-6.
    const size_t WS_NEED = (size_t)(2 * KEY_E + ATT_E + 2 * QW_E) * 2;

    if (ws_size >= WS_NEED && d_ws != nullptr) {
        u16* key_hi = (u16*)d_ws;
        u16* key_lo = key_hi + KEY_E;   // becomes key_hT after phase 2
        u16* att_b  = key_lo + KEY_E;
        u16* qW_hi  = att_b + ATT_E;
        u16* qW_lo  = qW_hi + QW_E;
        // phase-1 scratch aliased into att_b (all dead by softmax time):
        u16* q_hi   = att_b;
        u16* q_lo   = q_hi + QW_E;
        u16* W_hi   = q_lo + QW_E;
        u16* W_lo   = W_hi + W_E;
        u16* W_hiT  = W_lo + W_E;
        u16* W_loT  = W_hiT + W_E;

        // 0) split key / query / W into hi+lo bf16 planes (memory-bound)
        split_f32<<<dim3(4096), 256, 0, stream>>>(key, key_hi, key_lo, KEY_E / 4);
        split_f32<<<dim3(512),  256, 0, stream>>>(query, q_hi, q_lo, QW_E / 4);
        split_f32<<<dim3(1024), 256, 0, stream>>>(W, W_hi, W_lo, W_E / 4);

        // 0b) transpose W planes: [1024 k][1024 n] -> [1024 n][1024 k]
        transpose_bf16<<<dim3(16, 16, 1), 256, 0, stream>>>(W_hi, W_hiT, 1024, 1024);
        transpose_bf16<<<dim3(16, 16, 1), 256, 0, stream>>>(W_lo, W_loT, 1024, 1024);

        // 1) qW hi/lo = (query @ W) / 32   [512 x 1024], 128 blocks
        gemm_qw<<<dim3(16, 8, 1), 256, 0, stream>>>(
            q_hi, q_lo, W_hiT, W_loT, qW_hi, qW_lo);

        // 2) S[b] = qW @ key[b]^T    [512 x 2048], K=1024, split bf16 GEMM
        gemm_bf16<true><<<dim3(16, 4, 16), 256, 0, stream>>>(
            qW_hi, qW_lo, key_hi, key_lo, att,
            1024, 1024, 1024, 2048,
            0L, (long)2048 * 1024, (long)512 * 2048, 1.f);

        // 2b) transpose key_hi [b][2048 n][1024 d] -> key_hT [b][1024 d][2048 n]
        u16* key_hT = key_lo;
        transpose_bf16<<<dim3(16, 32, 16), 256, 0, stream>>>(
            key_hi, key_hT, 2048, 1024);

        // 3) masked softmax, dual-write f32 + bf16 (overwrites q/W scratch)
        softmax_rows<<<dim3(16 * 512), 256, 0, stream>>>(att, mask, att_b);

        // 4) out[b] = att[b] @ key[b]  [512 x 1024], K=2048, copy-staged GEMM
        gemm_bf16<false><<<dim3(8, 4, 16), 256, 0, stream>>>(
            att_b, nullptr, key_hT, nullptr, out,
            2048, 2048, 2048, 1024,
            (long)512 * 2048, (long)1024 * 2048, (long)512 * 1024, 1.f);
    } else {
        // -------- fallback: round-1 path, no workspace --------
        float* qW = out;    // f32 scratch in out region (dead before phase 4)
        gemm_f32conv<false, true><<<dim3(8, 4, 1), 256, 0, stream>>>(
            query, W, qW, 1024, 1024, 1024, 1024, 0L, 0L, 0L, 1.f / 32.f);
        gemm_f32conv<true, true><<<dim3(16, 4, 16), 256, 0, stream>>>(
            qW, key, att, 1024, 1024, 1024, 2048,
            0L, (long)2048 * 1024, (long)512 * 2048, 1.f);
        softmax_rows<<<dim3(16 * 512), 256, 0, stream>>>(att, mask, nullptr);
        gemm_f32conv<false, false><<<dim3(8, 4, 16), 256, 0, stream>>>(
            att, key, out, 2048, 2048, 1024, 1024,
            (long)512 * 2048, (long)2048 * 1024, (long)512 * 1024, 1.f);
    }
}

// Round 8
// 465.236 us; speedup vs baseline: 1.2917x; 1.1634x over previous
//
#include <hip/hip_runtime.h>

// SimpleConcatAttention on MI355X — round 8: fp16 single-plane pipeline.
// Round-7 post-mortem: phase 2 (3-term split-bf16) = 139 µs at ~740 TF, the
// 2-barrier-structure ceiling. Error analysis: measured absmax 2^-9 is the
// bf16 rounding of softmax p (att_b), NOT S-path error — the 3-term split's
// 2^-18 precision is overkill. fp16 (2^-11 rel, range safe for N(0,1) data)
// lets phase 2 run SINGLE-term: S err ~1e-3 absolute -> att err ≤ ~2e-4
// (softmax damping), while fp16 att_b/key shrink the dominant out-error 4x.
//   0) key f32 -> key_h fp16 (single plane)   [writes halve vs hi/lo]
//   0b) split q, W -> fp16 hi/lo; transpose W planes
//   1) qW = (q@W)/32: 3-term fp16-split GEMM -> qW fp16 (accuracy preserved)
//   2) S = qW@key^T: 1-term fp16 GEMM (16 MFMA/K-step, 2 planes staged)
//   2b) transpose key_h -> key_hT (key_lo slot)
//   3) softmax f32, dual-write f32 + fp16
//   4) out = att@key: 1-term fp16 GEMM with key_hT
// mfma_f32_16x16x32_f16: same rate and same C/D layout as bf16 (dtype-indep).
// Staging: round-7's measured-best reg-staged pad-40 + T14 prefetch.

typedef float f32x4 __attribute__((ext_vector_type(4)));
typedef short s16x8 __attribute__((ext_vector_type(8)));
typedef short s16x4 __attribute__((ext_vector_type(4)));
typedef _Float16 f16x8 __attribute__((ext_vector_type(8)));
typedef unsigned short u16;
typedef unsigned short u16x8 __attribute__((ext_vector_type(8)));

// ---- conversions (compiler-visible; no inline asm per m240 lesson) ----
__device__ __forceinline__ u16 f2h(float f) {           // f32 -> fp16 RNE
    _Float16 h = (_Float16)f;
    return __builtin_bit_cast(u16, h);
}
__device__ __forceinline__ float h2f(u16 v) {           // exact expand
    return (float)__builtin_bit_cast(_Float16, v);
}
__device__ __forceinline__ u16 f2bf(float f) {          // bf16 RNE (fallback path)
    unsigned int u = __float_as_uint(f);
    return (u16)((u + 0x7fffu + ((u >> 16) & 1u)) >> 16);
}
__device__ __forceinline__ float bf2f(u16 h) {
    return __uint_as_float(((unsigned int)h) << 16);
}

// Load 8 u16 (two 8B halves) from LDS at two precomputed u16 offsets.
__device__ __forceinline__ s16x8 ld2(const u16* p, int off1, int off2) {
    s16x4 a = *(const s16x4*)(p + off1);
    s16x4 b = *(const s16x4*)(p + off2);
    s16x8 r = {a[0], a[1], a[2], a[3], b[0], b[1], b[2], b[3]};
    return r;
}
__device__ __forceinline__ f16x8 ld2h(const u16* p, int off1, int off2) {
    return __builtin_bit_cast(f16x8, ld2(p, off1, off2));
}

// ===========================================================================
// Round-1 fused-conversion bf16 GEMM — fallback path only (ws too small).
// ===========================================================================
#define CSTR 36
typedef short bf16x8 __attribute__((ext_vector_type(8)));
__device__ __forceinline__ int swzc(int row, int k) {
    return row * CSTR + (k ^ (((row >> 2) & 7) << 2));
}
__device__ __forceinline__ bf16x8 ld_fragc(const u16* plane, int row, int kg) {
    s16x8 v = ld2(plane, swzc(row, kg), swzc(row, kg + 16));
    return __builtin_bit_cast(bf16x8, v);
}

template<bool BT, bool SPLIT>
__global__ __launch_bounds__(256, 2) void gemm_f32conv(
    const float* __restrict__ A, const float* __restrict__ B,
    float* __restrict__ C,
    int Kd, int lda, int ldb, int ldc,
    long sA, long sB, long sC, float scale)
{
    constexpr int PLANES = SPLIT ? 2 : 1;
    __shared__ u16 As[PLANES][128 * CSTR];
    __shared__ u16 Bs[PLANES][128 * CSTR];

    const int tid  = threadIdx.x;
    const int lane = tid & 63;
    const int wave = tid >> 6;
    const int wm = (wave >> 1) * 64, wn = (wave & 1) * 64;
    const int lr = lane & 15, kg = (lane >> 4) * 4;

    const int m0 = blockIdx.y * 128, n0 = blockIdx.x * 128;
    const float* Ag = A + (long)blockIdx.z * sA + (long)m0 * lda;
    const float* Bg = B + (long)blockIdx.z * sB + (BT ? (long)n0 * ldb : (long)n0);

    f32x4 acc[4][4] = {};

    for (int k0 = 0; k0 < Kd; k0 += 32) {
        __syncthreads();
#pragma unroll
        for (int it = 0; it < 4; it++) {
            const int idx = tid + it * 256;
            const int row = idx >> 3, kc = (idx & 7) * 4;
            f32x4 v = *(const f32x4*)(Ag + (long)row * lda + k0 + kc);
            ushort4 h;
            h.x = f2bf(v[0]); h.y = f2bf(v[1]); h.z = f2bf(v[2]); h.w = f2bf(v[3]);
            *(ushort4*)&As[0][swzc(row, kc)] = h;
            if constexpr (SPLIT) {
                ushort4 l;
                l.x = f2bf(v[0] - bf2f(h.x)); l.y = f2bf(v[1] - bf2f(h.y));
                l.z = f2bf(v[2] - bf2f(h.z)); l.w = f2bf(v[3] - bf2f(h.w));
                *(ushort4*)&As[1][swzc(row, kc)] = l;
            }
        }
        if constexpr (BT) {
#pragma unroll
            for (int it = 0; it < 4; it++) {
                const int idx = tid + it * 256;
                const int row = idx >> 3, kc = (idx & 7) * 4;
                f32x4 v = *(const f32x4*)(Bg + (long)row * ldb + k0 + kc);
                ushort4 h;
                h.x = f2bf(v[0]); h.y = f2bf(v[1]); h.z = f2bf(v[2]); h.w = f2bf(v[3]);
                *(ushort4*)&Bs[0][swzc(row, kc)] = h;
                if constexpr (SPLIT) {
                    ushort4 l;
                    l.x = f2bf(v[0] - bf2f(h.x)); l.y = f2bf(v[1] - bf2f(h.y));
                    l.z = f2bf(v[2] - bf2f(h.z)); l.w = f2bf(v[3] - bf2f(h.w));
                    *(ushort4*)&Bs[1][swzc(row, kc)] = l;
                }
            }
        } else {
#pragma unroll
            for (int it = 0; it < 2; it++) {
                const int idx = tid + it * 256;
                const int kk = (idx >> 5) * 2;
                const int nc = (idx & 31) * 4;
                f32x4 v0 = *(const f32x4*)(Bg + (long)(k0 + kk) * ldb + nc);
                f32x4 v1 = *(const f32x4*)(Bg + (long)(k0 + kk + 1) * ldb + nc);
#pragma unroll
                for (int e = 0; e < 4; e++) {
                    const u16 h0 = f2bf(v0[e]), h1 = f2bf(v1[e]);
                    *(unsigned*)&Bs[0][swzc(nc + e, kk)] =
                        (unsigned)h0 | ((unsigned)h1 << 16);
                    if constexpr (SPLIT) {
                        const u16 l0 = f2bf(v0[e] - bf2f(h0));
                        const u16 l1 = f2bf(v1[e] - bf2f(h1));
                        *(unsigned*)&Bs[1][swzc(nc + e, kk)] =
                            (unsigned)l0 | ((unsigned)l1 << 16);
                    }
                }
            }
        }
        __syncthreads();

        bf16x8 ah[4], bh[4], al[4], bl[4];
#pragma unroll
        for (int i = 0; i < 4; i++) {
            ah[i] = ld_fragc(&As[0][0], wm + i * 16 + lr, kg);
            if constexpr (SPLIT) al[i] = ld_fragc(&As[1][0], wm + i * 16 + lr, kg);
        }
#pragma unroll
        for (int j = 0; j < 4; j++) {
            bh[j] = ld_fragc(&Bs[0][0], wn + j * 16 + lr, kg);
            if constexpr (SPLIT) bl[j] = ld_fragc(&Bs[1][0], wn + j * 16 + lr, kg);
        }
#pragma unroll
        for (int i = 0; i < 4; i++)
#pragma unroll
            for (int j = 0; j < 4; j++) {
                acc[i][j] = __builtin_amdgcn_mfma_f32_16x16x32_bf16(
                    ah[i], bh[j], acc[i][j], 0, 0, 0);
                if constexpr (SPLIT) {
                    acc[i][j] = __builtin_amdgcn_mfma_f32_16x16x32_bf16(
                        ah[i], bl[j], acc[i][j], 0, 0, 0);
                    acc[i][j] = __builtin_amdgcn_mfma_f32_16x16x32_bf16(
                        al[i], bh[j], acc[i][j], 0, 0, 0);
                }
            }
    }

    float* Cg = C + (long)blockIdx.z * sC + (long)(m0 + wm) * ldc + n0 + wn;
    const int rbase = (lane >> 4) * 4;
#pragma unroll
    for (int i = 0; i < 4; i++)
#pragma unroll
        for (int r = 0; r < 4; r++) {
            float* cp = Cg + (long)(i * 16 + rbase + r) * ldc + lr;
#pragma unroll
            for (int j = 0; j < 4; j++)
                cp[j * 16] = acc[i][j][r] * scale;
        }
}

// ===========================================================================
// Elementwise converters.
// ===========================================================================
__global__ __launch_bounds__(256) void conv_f16(
    const float* __restrict__ src, u16* __restrict__ dst, long n4)
{
    const long stride = (long)gridDim.x * 256;
    for (long i = (long)blockIdx.x * 256 + threadIdx.x; i < n4; i += stride) {
        f32x4 v = *(const f32x4*)(src + i * 4);
        ushort4 h;
        h.x = f2h(v[0]); h.y = f2h(v[1]); h.z = f2h(v[2]); h.w = f2h(v[3]);
        *(ushort4*)(dst + i * 4) = h;
    }
}

__global__ __launch_bounds__(256) void split_f16(
    const float* __restrict__ src, u16* __restrict__ hi, u16* __restrict__ lo,
    long n4)
{
    const long stride = (long)gridDim.x * 256;
    for (long i = (long)blockIdx.x * 256 + threadIdx.x; i < n4; i += stride) {
        f32x4 v = *(const f32x4*)(src + i * 4);
        ushort4 h, l;
        h.x = f2h(v[0]); h.y = f2h(v[1]); h.z = f2h(v[2]); h.w = f2h(v[3]);
        l.x = f2h(v[0] - h2f(h.x)); l.y = f2h(v[1] - h2f(h.y));
        l.z = f2h(v[2] - h2f(h.z)); l.w = f2h(v[3] - h2f(h.w));
        *(ushort4*)(hi + i * 4) = h;
        *(ushort4*)(lo + i * 4) = l;
    }
}

// ===========================================================================
// Tiled u16 transpose: in [Z][R][C] -> out [Z][C][R]. R,C multiples of 64.
// ===========================================================================
__global__ __launch_bounds__(256) void transpose_u16(
    const u16* __restrict__ in, u16* __restrict__ out, int R, int C)
{
    __shared__ u16 T[64 * 72];                  // stride 72 u16 (16B-align rows)
    const int tid = threadIdx.x;
    const int c0 = blockIdx.x * 64, r0 = blockIdx.y * 64;
    const long zoff = (long)blockIdx.z * R * C;
    const u16* src = in + zoff + (long)r0 * C + c0;
#pragma unroll
    for (int it = 0; it < 2; it++) {
        const int r = it * 32 + (tid >> 3), c = (tid & 7) * 8;
        u16x8 v = *(const u16x8*)(src + (long)r * C + c);
#pragma unroll
        for (int j = 0; j < 8; j++) T[(c + j) * 72 + r] = v[j];
    }
    __syncthreads();
    u16* dst = out + zoff + (long)c0 * R + r0;
#pragma unroll
    for (int it = 0; it < 2; it++) {
        const int c = it * 32 + (tid >> 3), r = (tid & 7) * 8;
        *(u16x8*)(dst + (long)c * R + r) = *(const u16x8*)&T[c * 72 + r];
    }
}

// ===========================================================================
// fp16-input MFMA GEMM, single-plane, both operands k-contiguous, reg-staged
// (pad-40) with T14 prefetch (round-7 measured-best staging).
// A: [M][lda] fp16, B: [N][ldb] fp16. Tile 128x128, BK=32, 4 waves (64x64).
// ===========================================================================
#define ASTR 40
__global__ __launch_bounds__(256, 3) void gemm_f16(
    const u16* __restrict__ A, const u16* __restrict__ B,
    float* __restrict__ C,
    int Kd, int lda, int ldb, int ldc,
    long sA, long sB, long sC, float scale)
{
    __shared__ u16 As[128 * ASTR];
    __shared__ u16 Bs[128 * ASTR];

    const int tid  = threadIdx.x;
    const int lane = tid & 63;
    const int wave = tid >> 6;
    const int wm = (wave >> 1) * 64, wn = (wave & 1) * 64;
    const int lr = lane & 15, kg = (lane >> 4) * 4;

    const int m0 = blockIdx.y * 128, n0 = blockIdx.x * 128;
    const u16* Ag = A + (long)blockIdx.z * sA + (long)m0 * lda;
    const u16* Bg = B + (long)blockIdx.z * sB + (long)n0 * ldb;

    // Per-thread staging coords: rows srow, srow+64; 8 fp16 at col scol.
    const int srow = tid >> 2, scol = (tid & 3) * 8;

    // Prefetch registers (static indices only — rule #20).
    u16x8 ra[2], rb[2];
#pragma unroll
    for (int it = 0; it < 2; it++) {
        ra[it] = *(const u16x8*)(Ag + (long)(srow + it * 64) * lda + scol);
        rb[it] = *(const u16x8*)(Bg + (long)(srow + it * 64) * ldb + scol);
    }

    f32x4 acc[4][4] = {};

    for (int k0 = 0; k0 < Kd; k0 += 32) {
        __syncthreads();
        // ---- STAGE_WRITE: regs (tile k0) -> LDS ----
#pragma unroll
        for (int it = 0; it < 2; it++) {
            *(u16x8*)&As[(srow + it * 64) * ASTR + scol] = ra[it];
            *(u16x8*)&Bs[(srow + it * 64) * ASTR + scol] = rb[it];
        }
        __syncthreads();

        // ---- STAGE_LOAD (T14): issue tile k0+32 loads before the MFMA phase ----
        if (k0 + 32 < Kd) {
            const int kn = k0 + 32;
#pragma unroll
            for (int it = 0; it < 2; it++) {
                ra[it] = *(const u16x8*)(Ag + (long)(srow + it * 64) * lda + kn + scol);
                rb[it] = *(const u16x8*)(Bg + (long)(srow + it * 64) * ldb + kn + scol);
            }
        }

        // ---- fragment loads ----
        f16x8 af[4], bfr[4];
#pragma unroll
        for (int i = 0; i < 4; i++) {
            const int r = wm + i * 16 + lr;
            af[i] = ld2h(As, r * ASTR + kg, r * ASTR + kg + 16);
        }
#pragma unroll
        for (int j = 0; j < 4; j++) {
            const int r = wn + j * 16 + lr;
            bfr[j] = ld2h(Bs, r * ASTR + kg, r * ASTR + kg + 16);
        }

        // ---- MFMA (single term) ----
#pragma unroll
        for (int i = 0; i < 4; i++)
#pragma unroll
            for (int j = 0; j < 4; j++)
                acc[i][j] = __builtin_amdgcn_mfma_f32_16x16x32_f16(
                    af[i], bfr[j], acc[i][j], 0, 0, 0);
    }

    // ---- epilogue: C/D layout col=lane&15, row=(lane>>4)*4+reg ----
    float* Cg = C + (long)blockIdx.z * sC + (long)(m0 + wm) * ldc + n0 + wn;
    const int rbase = (lane >> 4) * 4;
#pragma unroll
    for (int i = 0; i < 4; i++)
#pragma unroll
        for (int r = 0; r < 4; r++) {
            float* cp = Cg + (long)(i * 16 + rbase + r) * ldc + lr;
#pragma unroll
            for (int j = 0; j < 4; j++)
                cp[j * 16] = acc[i][j][r] * scale;
        }
}

// ===========================================================================
// Phase-1 kernel: qW = (query @ W)/32, 3-term fp16-split in, fp16 OUT.
// M=512, N=1024, K=1024, B = W^T planes [n][k]. Tile 64x64, 4 waves (32x32),
// 128 blocks; copy staging (pad-40), both operands k-contiguous.
// ===========================================================================
__global__ __launch_bounds__(256, 2) void gemm_qw(
    const u16* __restrict__ qh, const u16* __restrict__ ql,
    const u16* __restrict__ WhT, const u16* __restrict__ WlT,
    u16* __restrict__ qWh)
{
    __shared__ u16 As[2][64 * ASTR];
    __shared__ u16 Bs[2][64 * ASTR];

    const int tid  = threadIdx.x;
    const int lane = tid & 63;
    const int wave = tid >> 6;
    const int wm = (wave >> 1) * 32, wn = (wave & 1) * 32;
    const int lr = lane & 15, kg = (lane >> 4) * 4;
    const int m0 = blockIdx.y * 64, n0 = blockIdx.x * 64;

    const u16* Ag[2] = { qh + (long)m0 * 1024, ql + (long)m0 * 1024 };
    const u16* Bg[2] = { WhT + (long)n0 * 1024, WlT + (long)n0 * 1024 };

    f32x4 acc[2][2] = {};

    for (int k0 = 0; k0 < 1024; k0 += 32) {
        __syncthreads();
        const int row = tid >> 2, kc = (tid & 3) * 8;   // 64 rows x 32 k per plane
#pragma unroll
        for (int p = 0; p < 2; p++) {
            *(u16x8*)&As[p][row * ASTR + kc] =
                *(const u16x8*)(Ag[p] + (long)row * 1024 + k0 + kc);
            *(u16x8*)&Bs[p][row * ASTR + kc] =
                *(const u16x8*)(Bg[p] + (long)row * 1024 + k0 + kc);
        }
        __syncthreads();

        f16x8 af[2][2], bfr[2][2];
#pragma unroll
        for (int i = 0; i < 2; i++) {
            const int r = wm + i * 16 + lr;
#pragma unroll
            for (int p = 0; p < 2; p++)
                af[p][i] = ld2h(&As[p][0], r * ASTR + kg, r * ASTR + kg + 16);
        }
#pragma unroll
        for (int j = 0; j < 2; j++) {
            const int r = wn + j * 16 + lr;
#pragma unroll
            for (int p = 0; p < 2; p++)
                bfr[p][j] = ld2h(&Bs[p][0], r * ASTR + kg, r * ASTR + kg + 16);
        }
#pragma unroll
        for (int i = 0; i < 2; i++)
#pragma unroll
            for (int j = 0; j < 2; j++) {
                acc[i][j] = __builtin_amdgcn_mfma_f32_16x16x32_f16(
                    af[0][i], bfr[0][j], acc[i][j], 0, 0, 0);
                acc[i][j] = __builtin_amdgcn_mfma_f32_16x16x32_f16(
                    af[0][i], bfr[1][j], acc[i][j], 0, 0, 0);
                acc[i][j] = __builtin_amdgcn_mfma_f32_16x16x32_f16(
                    af[1][i], bfr[0][j], acc[i][j], 0, 0, 0);
            }
    }

    // Epilogue: scale by 1/32, write fp16 qW.
    const int rbase = (lane >> 4) * 4;
#pragma unroll
    for (int i = 0; i < 2; i++)
#pragma unroll
        for (int r = 0; r < 4; r++) {
            const long ro = (long)(m0 + wm + i * 16 + rbase + r) * 1024 + n0 + wn + lr;
#pragma unroll
            for (int j = 0; j < 2; j++)
                qWh[ro + j * 16] = f2h(acc[i][j][r] * (1.f / 32.f));
        }
}

// ===========================================================================
// Masked softmax over rows of 2048, in place on f32 scores; optionally also
// writes an fp16 copy (phase-4 A operand). One block per row.
// ===========================================================================
__global__ __launch_bounds__(256) void softmax_rows(
    float* __restrict__ att, const int* __restrict__ mask, u16* __restrict__ ahf)
{
    const int  row  = blockIdx.x;                    // b*512 + k
    const int  tid  = threadIdx.x;
    const long base = (long)row * 2048 + tid * 8;

    f32x4 s0 = *(const f32x4*)(att + base);
    f32x4 s1 = *(const f32x4*)(att + base + 4);
    int4  mv0 = *(const int4*)(mask + base);
    int4  mv1 = *(const int4*)(mask + base + 4);
    const int mk[8] = {mv0.x, mv0.y, mv0.z, mv0.w, mv1.x, mv1.y, mv1.z, mv1.w};

    float x[8] = {s0[0], s0[1], s0[2], s0[3], s1[0], s1[1], s1[2], s1[3]};
#pragma unroll
    for (int j = 0; j < 8; j++) x[j] = mk[j] ? x[j] : -INFINITY;

    float mx = x[0];
#pragma unroll
    for (int j = 1; j < 8; j++) mx = fmaxf(mx, x[j]);
#pragma unroll
    for (int off = 32; off > 0; off >>= 1) mx = fmaxf(mx, __shfl_down(mx, off));

    __shared__ float red[8];
    const int wave = tid >> 6, lane = tid & 63;
    if (lane == 0) red[wave] = mx;
    __syncthreads();
    mx = fmaxf(fmaxf(red[0], red[1]), fmaxf(red[2], red[3]));

    if (mx == -INFINITY) {                           // all-masked row: zeros, not NaN
        f32x4 z = {0.f, 0.f, 0.f, 0.f};
        *(f32x4*)(att + base) = z;
        *(f32x4*)(att + base + 4) = z;
        if (ahf) {
            u16x8 zh = {0, 0, 0, 0, 0, 0, 0, 0};
            *(u16x8*)(ahf + base) = zh;
        }
        return;
    }

    float e[8], s = 0.f;
#pragma unroll
    for (int j = 0; j < 8; j++) { e[j] = __expf(x[j] - mx); s += e[j]; }
#pragma unroll
    for (int off = 32; off > 0; off >>= 1) s += __shfl_down(s, off);
    if (lane == 0) red[4 + wave] = s;
    __syncthreads();
    s = red[4] + red[5] + red[6] + red[7];

    const float inv = 1.f / s;
    float o[8];
#pragma unroll
    for (int j = 0; j < 8; j++) o[j] = e[j] * inv;
    f32x4 o0 = {o[0], o[1], o[2], o[3]}, o1 = {o[4], o[5], o[6], o[7]};
    *(f32x4*)(att + base) = o0;
    *(f32x4*)(att + base + 4) = o1;
    if (ahf) {
        u16x8 ph;
#pragma unroll
        for (int j = 0; j < 8; j++) ph[j] = f2h(o[j]);
        *(u16x8*)(ahf + base) = ph;
    }
}

// ===========================================================================
extern "C" void kernel_launch(void* const* d_in, const int* in_sizes, int n_in,
                              void* d_out, int out_size, void* d_ws, size_t ws_size,
                              hipStream_t stream)
{
    const float* query = nullptr;   // 512*1024      = 524288
    const float* key   = nullptr;   // 16*2048*1024  = 33554432
    const float* W     = nullptr;   // 1024*1024     = 1048576
    const int*   mask  = nullptr;   // 16*512*2048   = 16777216
    for (int i = 0; i < n_in; i++) {
        switch (in_sizes[i]) {
            case 524288:   query = (const float*)d_in[i]; break;
            case 33554432: key   = (const float*)d_in[i]; break;
            case 1048576:  W     = (const float*)d_in[i]; break;
            case 16777216: mask  = (const int*)d_in[i];   break;
        }
    }

    float* out = (float*)d_out;                     // [16,512,1024] f32
    float* att = out + (long)16 * 512 * 1024;       // [16,512,2048] f32

    const long KEY_E = 16L * 2048 * 1024;           // 33,554,432
    const long ATT_E = 16L * 512 * 2048;            // 16,777,216
    const long QW_E  = 512L * 1024;                 //    524,288
    const long W_E   = 1024L * 1024;                //  1,048,576
    // ws layout (same footprint/guard as rounds 4-7):
    //   key_h | key_hT | att_h | qW_h | (spare)
    // Phase-1 scratch (q hi/lo, W hi/lo, W^T hi/lo) aliases into att_h region
    // (dead until softmax; 5.25M u16 <= 16.8M u16).
    const size_t WS_NEED = (size_t)(2 * KEY_E + ATT_E + 2 * QW_E) * 2;

    if (ws_size >= WS_NEED && d_ws != nullptr) {
        u16* key_h  = (u16*)d_ws;
        u16* key_hT = key_h + KEY_E;
        u16* att_h  = key_hT + KEY_E;
        u16* qW_h   = att_h + ATT_E;
        // phase-1 scratch aliased into att_h (all dead by softmax time):
        u16* q_hi   = att_h;
        u16* q_lo   = q_hi + QW_E;
        u16* W_hi   = q_lo + QW_E;
        u16* W_lo   = W_hi + W_E;
        u16* W_hiT  = W_lo + W_E;
        u16* W_loT  = W_hiT + W_E;

        // 0) key f32 -> fp16 (single plane); q/W -> fp16 hi+lo splits
        conv_f16<<<dim3(4096), 256, 0, stream>>>(key, key_h, KEY_E / 4);
        split_f16<<<dim3(512),  256, 0, stream>>>(query, q_hi, q_lo, QW_E / 4);
        split_f16<<<dim3(1024), 256, 0, stream>>>(W, W_hi, W_lo, W_E / 4);

        // 0b) transpose W planes: [1024 k][1024 n] -> [1024 n][1024 k]
        transpose_u16<<<dim3(16, 16, 1), 256, 0, stream>>>(W_hi, W_hiT, 1024, 1024);
        transpose_u16<<<dim3(16, 16, 1), 256, 0, stream>>>(W_lo, W_loT, 1024, 1024);

        // 1) qW = (query @ W) / 32  [512 x 1024], 3-term fp16 split, fp16 out
        gemm_qw<<<dim3(16, 8, 1), 256, 0, stream>>>(
            q_hi, q_lo, W_hiT, W_loT, qW_h);

        // 2) S[b] = qW @ key[b]^T   [512 x 2048], K=1024, 1-term fp16 GEMM
        gemm_f16<<<dim3(16, 4, 16), 256, 0, stream>>>(
            qW_h, key_h, att,
            1024, 1024, 1024, 2048,
            0L, (long)2048 * 1024, (long)512 * 2048, 1.f);

        // 2b) transpose key_h [b][2048 n][1024 d] -> key_hT [b][1024 d][2048 n]
        transpose_u16<<<dim3(16, 32, 16), 256, 0, stream>>>(
            key_h, key_hT, 2048, 1024);

        // 3) masked softmax, dual-write f32 + fp16 (overwrites q/W scratch)
        softmax_rows<<<dim3(16 * 512), 256, 0, stream>>>(att, mask, att_h);

        // 4) out[b] = att[b] @ key[b]  [512 x 1024], K=2048, 1-term fp16 GEMM
        gemm_f16<<<dim3(8, 4, 16), 256, 0, stream>>>(
            att_h, key_hT, out,
            2048, 2048, 2048, 1024,
            (long)512 * 2048, (long)1024 * 2048, (long)512 * 1024, 1.f);
    } else {
        // -------- fallback: round-1 bf16 path, no workspace --------
        float* qW = out;    // f32 scratch in out region (dead before phase 4)
        gemm_f32conv<false, true><<<dim3(8, 4, 1), 256, 0, stream>>>(
            query, W, qW, 1024, 1024, 1024, 1024, 0L, 0L, 0L, 1.f / 32.f);
        gemm_f32conv<true, true><<<dim3(16, 4, 16), 256, 0, stream>>>(
            qW, key, att, 1024, 1024, 1024, 2048,
            0L, (long)2048 * 1024, (long)512 * 2048, 1.f);
        softmax_rows<<<dim3(16 * 512), 256, 0, stream>>>(att, mask, nullptr);
        gemm_f32conv<false, false><<<dim3(8, 4, 16), 256, 0, stream>>>(
            att, key, out, 2048, 2048, 1024, 1024,
            (long)512 * 2048, (long)2048 * 1024, (long)512 * 1024, 1.f);
    }
}

// Round 9
// 456.629 us; speedup vs baseline: 1.3161x; 1.0188x over previous
//
#include <hip/hip_runtime.h>

// SimpleConcatAttention on MI355X — round 9: BK=64 GEMM + fused key transpose.
// Round-8 post-mortem: fp16 1-term pipeline hit 465 µs, absmax unchanged —
// but gemm_f16 runs at MfmaUtil 17% (440 TF): dropping 48->16 MFMA/K-step left
// the 2-barrier+staging overhead amortized over 3x less math.
// Round 9: (a) BK=64 — 32 MFMA per staging round, half the barriers (same
// total staged bytes); (b) key conversion writes key_h AND key_hT in one pass
// (LDS-transposed tile), deleting the separate 134 MB transpose dispatch.
// Pipeline: conv_key (h + hT) | split q,W + W^T | qW 3-term fp16 | S 1-term |
// softmax f32 (dual write f32+fp16) | out 1-term with key_hT.
// Fallback (ws too small): round-1 bf16 fused-conversion path.

typedef float f32x4 __attribute__((ext_vector_type(4)));
typedef short s16x8 __attribute__((ext_vector_type(8)));
typedef short s16x4 __attribute__((ext_vector_type(4)));
typedef _Float16 f16x8 __attribute__((ext_vector_type(8)));
typedef unsigned short u16;
typedef unsigned short u16x8 __attribute__((ext_vector_type(8)));

// ---- conversions (compiler-visible; no inline asm per m240 lesson) ----
__device__ __forceinline__ u16 f2h(float f) {           // f32 -> fp16 RNE
    _Float16 h = (_Float16)f;
    return __builtin_bit_cast(u16, h);
}
__device__ __forceinline__ float h2f(u16 v) {           // exact expand
    return (float)__builtin_bit_cast(_Float16, v);
}
__device__ __forceinline__ u16 f2bf(float f) {          // bf16 RNE (fallback path)
    unsigned int u = __float_as_uint(f);
    return (u16)((u + 0x7fffu + ((u >> 16) & 1u)) >> 16);
}
__device__ __forceinline__ float bf2f(u16 h) {
    return __uint_as_float(((unsigned int)h) << 16);
}

// Load 8 u16 (two 8B halves) from LDS at two precomputed u16 offsets.
__device__ __forceinline__ s16x8 ld2(const u16* p, int off1, int off2) {
    s16x4 a = *(const s16x4*)(p + off1);
    s16x4 b = *(const s16x4*)(p + off2);
    s16x8 r = {a[0], a[1], a[2], a[3], b[0], b[1], b[2], b[3]};
    return r;
}
__device__ __forceinline__ f16x8 ld2h(const u16* p, int off1, int off2) {
    return __builtin_bit_cast(f16x8, ld2(p, off1, off2));
}

// ===========================================================================
// Round-1 fused-conversion bf16 GEMM — fallback path only (ws too small).
// ===========================================================================
#define CSTR 36
typedef short bf16x8 __attribute__((ext_vector_type(8)));
__device__ __forceinline__ int swzc(int row, int k) {
    return row * CSTR + (k ^ (((row >> 2) & 7) << 2));
}
__device__ __forceinline__ bf16x8 ld_fragc(const u16* plane, int row, int kg) {
    s16x8 v = ld2(plane, swzc(row, kg), swzc(row, kg + 16));
    return __builtin_bit_cast(bf16x8, v);
}

template<bool BT, bool SPLIT>
__global__ __launch_bounds__(256, 2) void gemm_f32conv(
    const float* __restrict__ A, const float* __restrict__ B,
    float* __restrict__ C,
    int Kd, int lda, int ldb, int ldc,
    long sA, long sB, long sC, float scale)
{
    constexpr int PLANES = SPLIT ? 2 : 1;
    __shared__ u16 As[PLANES][128 * CSTR];
    __shared__ u16 Bs[PLANES][128 * CSTR];

    const int tid  = threadIdx.x;
    const int lane = tid & 63;
    const int wave = tid >> 6;
    const int wm = (wave >> 1) * 64, wn = (wave & 1) * 64;
    const int lr = lane & 15, kg = (lane >> 4) * 4;

    const int m0 = blockIdx.y * 128, n0 = blockIdx.x * 128;
    const float* Ag = A + (long)blockIdx.z * sA + (long)m0 * lda;
    const float* Bg = B + (long)blockIdx.z * sB + (BT ? (long)n0 * ldb : (long)n0);

    f32x4 acc[4][4] = {};

    for (int k0 = 0; k0 < Kd; k0 += 32) {
        __syncthreads();
#pragma unroll
        for (int it = 0; it < 4; it++) {
            const int idx = tid + it * 256;
            const int row = idx >> 3, kc = (idx & 7) * 4;
            f32x4 v = *(const f32x4*)(Ag + (long)row * lda + k0 + kc);
            ushort4 h;
            h.x = f2bf(v[0]); h.y = f2bf(v[1]); h.z = f2bf(v[2]); h.w = f2bf(v[3]);
            *(ushort4*)&As[0][swzc(row, kc)] = h;
            if constexpr (SPLIT) {
                ushort4 l;
                l.x = f2bf(v[0] - bf2f(h.x)); l.y = f2bf(v[1] - bf2f(h.y));
                l.z = f2bf(v[2] - bf2f(h.z)); l.w = f2bf(v[3] - bf2f(h.w));
                *(ushort4*)&As[1][swzc(row, kc)] = l;
            }
        }
        if constexpr (BT) {
#pragma unroll
            for (int it = 0; it < 4; it++) {
                const int idx = tid + it * 256;
                const int row = idx >> 3, kc = (idx & 7) * 4;
                f32x4 v = *(const f32x4*)(Bg + (long)row * ldb + k0 + kc);
                ushort4 h;
                h.x = f2bf(v[0]); h.y = f2bf(v[1]); h.z = f2bf(v[2]); h.w = f2bf(v[3]);
                *(ushort4*)&Bs[0][swzc(row, kc)] = h;
                if constexpr (SPLIT) {
                    ushort4 l;
                    l.x = f2bf(v[0] - bf2f(h.x)); l.y = f2bf(v[1] - bf2f(h.y));
                    l.z = f2bf(v[2] - bf2f(h.z)); l.w = f2bf(v[3] - bf2f(h.w));
                    *(ushort4*)&Bs[1][swzc(row, kc)] = l;
                }
            }
        } else {
#pragma unroll
            for (int it = 0; it < 2; it++) {
                const int idx = tid + it * 256;
                const int kk = (idx >> 5) * 2;
                const int nc = (idx & 31) * 4;
                f32x4 v0 = *(const f32x4*)(Bg + (long)(k0 + kk) * ldb + nc);
                f32x4 v1 = *(const f32x4*)(Bg + (long)(k0 + kk + 1) * ldb + nc);
#pragma unroll
                for (int e = 0; e < 4; e++) {
                    const u16 h0 = f2bf(v0[e]), h1 = f2bf(v1[e]);
                    *(unsigned*)&Bs[0][swzc(nc + e, kk)] =
                        (unsigned)h0 | ((unsigned)h1 << 16);
                    if constexpr (SPLIT) {
                        const u16 l0 = f2bf(v0[e] - bf2f(h0));
                        const u16 l1 = f2bf(v1[e] - bf2f(h1));
                        *(unsigned*)&Bs[1][swzc(nc + e, kk)] =
                            (unsigned)l0 | ((unsigned)l1 << 16);
                    }
                }
            }
        }
        __syncthreads();

        bf16x8 ah[4], bh[4], al[4], bl[4];
#pragma unroll
        for (int i = 0; i < 4; i++) {
            ah[i] = ld_fragc(&As[0][0], wm + i * 16 + lr, kg);
            if constexpr (SPLIT) al[i] = ld_fragc(&As[1][0], wm + i * 16 + lr, kg);
        }
#pragma unroll
        for (int j = 0; j < 4; j++) {
            bh[j] = ld_fragc(&Bs[0][0], wn + j * 16 + lr, kg);
            if constexpr (SPLIT) bl[j] = ld_fragc(&Bs[1][0], wn + j * 16 + lr, kg);
        }
#pragma unroll
        for (int i = 0; i < 4; i++)
#pragma unroll
            for (int j = 0; j < 4; j++) {
                acc[i][j] = __builtin_amdgcn_mfma_f32_16x16x32_bf16(
                    ah[i], bh[j], acc[i][j], 0, 0, 0);
                if constexpr (SPLIT) {
                    acc[i][j] = __builtin_amdgcn_mfma_f32_16x16x32_bf16(
                        ah[i], bl[j], acc[i][j], 0, 0, 0);
                    acc[i][j] = __builtin_amdgcn_mfma_f32_16x16x32_bf16(
                        al[i], bh[j], acc[i][j], 0, 0, 0);
                }
            }
    }

    float* Cg = C + (long)blockIdx.z * sC + (long)(m0 + wm) * ldc + n0 + wn;
    const int rbase = (lane >> 4) * 4;
#pragma unroll
    for (int i = 0; i < 4; i++)
#pragma unroll
        for (int r = 0; r < 4; r++) {
            float* cp = Cg + (long)(i * 16 + rbase + r) * ldc + lr;
#pragma unroll
            for (int j = 0; j < 4; j++)
                cp[j * 16] = acc[i][j][r] * scale;
        }
}

// ===========================================================================
// split: src f32 -> fp16 hi/lo planes (q, W). n4 = elems/4.
// ===========================================================================
__global__ __launch_bounds__(256) void split_f16(
    const float* __restrict__ src, u16* __restrict__ hi, u16* __restrict__ lo,
    long n4)
{
    const long stride = (long)gridDim.x * 256;
    for (long i = (long)blockIdx.x * 256 + threadIdx.x; i < n4; i += stride) {
        f32x4 v = *(const f32x4*)(src + i * 4);
        ushort4 h, l;
        h.x = f2h(v[0]); h.y = f2h(v[1]); h.z = f2h(v[2]); h.w = f2h(v[3]);
        l.x = f2h(v[0] - h2f(h.x)); l.y = f2h(v[1] - h2f(h.y));
        l.z = f2h(v[2] - h2f(h.z)); l.w = f2h(v[3] - h2f(h.w));
        *(ushort4*)(hi + i * 4) = h;
        *(ushort4*)(lo + i * 4) = l;
    }
}

// ===========================================================================
// Fused key converter: f32 key [Z][2048 n][1024 d] -> fp16 key_h (same layout)
// AND fp16 key_hT [Z][1024 d][2048 n] (via LDS 64x64 transpose tile).
// One read of key, both fp16 planes written — replaces conv + transpose passes.
// ===========================================================================
__global__ __launch_bounds__(256) void conv_key(
    const float* __restrict__ key, u16* __restrict__ kh, u16* __restrict__ khT)
{
    __shared__ u16 T[64 * 72];                  // stride 72 u16 (16B-align rows)
    const int tid = threadIdx.x;
    const int d0 = blockIdx.x * 64;             // 16 blocks over d=1024
    const int n0 = blockIdx.y * 64;             // 32 blocks over n=2048
    const long zo = (long)blockIdx.z * 2048 * 1024;

    const float* src = key + zo + (long)n0 * 1024 + d0;
    u16* dh = kh + zo + (long)n0 * 1024 + d0;
#pragma unroll
    for (int it = 0; it < 2; it++) {
        const int r = it * 32 + (tid >> 3);     // n-row within tile
        const int c = (tid & 7) * 8;            // d-col within tile
        f32x4 v0 = *(const f32x4*)(src + (long)r * 1024 + c);
        f32x4 v1 = *(const f32x4*)(src + (long)r * 1024 + c + 4);
        u16 h[8];
#pragma unroll
        for (int j = 0; j < 4; j++) { h[j] = f2h(v0[j]); h[4 + j] = f2h(v1[j]); }
        u16x8 hv = {h[0], h[1], h[2], h[3], h[4], h[5], h[6], h[7]};
        *(u16x8*)(dh + (long)r * 1024 + c) = hv;          // straight fp16 write
#pragma unroll
        for (int j = 0; j < 8; j++) T[(c + j) * 72 + r] = h[j];  // transpose stage
    }
    __syncthreads();
    u16* dt = khT + zo + (long)d0 * 2048 + n0;
#pragma unroll
    for (int it = 0; it < 2; it++) {
        const int c = it * 32 + (tid >> 3);     // d-col within tile
        const int r = (tid & 7) * 8;            // n within tile
        *(u16x8*)(dt + (long)c * 2048 + r) = *(const u16x8*)&T[c * 72 + r];
    }
}

// ===========================================================================
// Tiled u16 transpose (W planes): in [R][C] -> out [C][R].
// ===========================================================================
__global__ __launch_bounds__(256) void transpose_u16(
    const u16* __restrict__ in, u16* __restrict__ out, int R, int C)
{
    __shared__ u16 T[64 * 72];
    const int tid = threadIdx.x;
    const int c0 = blockIdx.x * 64, r0 = blockIdx.y * 64;
    const u16* src = in + (long)r0 * C + c0;
#pragma unroll
    for (int it = 0; it < 2; it++) {
        const int r = it * 32 + (tid >> 3), c = (tid & 7) * 8;
        u16x8 v = *(const u16x8*)(src + (long)r * C + c);
#pragma unroll
        for (int j = 0; j < 8; j++) T[(c + j) * 72 + r] = v[j];
    }
    __syncthreads();
    u16* dst = out + (long)c0 * R + r0;
#pragma unroll
    for (int it = 0; it < 2; it++) {
        const int c = it * 32 + (tid >> 3), r = (tid & 7) * 8;
        *(u16x8*)(dst + (long)c * R + r) = *(const u16x8*)&T[c * 72 + r];
    }
}

// ===========================================================================
// fp16 MFMA GEMM, BK=64: both operands k-contiguous, reg-staged (pad-72) with
// T14 prefetch. 32 MFMA per staging round — half the barriers of BK=32.
// A: [M][lda] fp16, B: [N][ldb] fp16. Tile 128x128, 4 waves (64x64 each).
// ===========================================================================
#define ASTR2 72
__global__ __launch_bounds__(256, 3) void gemm_f16(
    const u16* __restrict__ A, const u16* __restrict__ B,
    float* __restrict__ C,
    int Kd, int lda, int ldb, int ldc,
    long sA, long sB, long sC, float scale)
{
    __shared__ u16 As[128 * ASTR2];
    __shared__ u16 Bs[128 * ASTR2];

    const int tid  = threadIdx.x;
    const int lane = tid & 63;
    const int wave = tid >> 6;
    const int wm = (wave >> 1) * 64, wn = (wave & 1) * 64;
    const int lr = lane & 15, kg = (lane >> 4) * 4;

    const int m0 = blockIdx.y * 128, n0 = blockIdx.x * 128;
    const u16* Ag = A + (long)blockIdx.z * sA + (long)m0 * lda;
    const u16* Bg = B + (long)blockIdx.z * sB + (long)n0 * ldb;

    // Per-thread staging coords: row srow (2 threads/row), 32 cols at scol.
    const int srow = tid >> 1, scol = (tid & 1) * 32;

    // Prefetch registers (static indices only — rule #20): 4 x 16B per operand.
    u16x8 ra[4], rb[4];
#pragma unroll
    for (int it = 0; it < 4; it++) {
        ra[it] = *(const u16x8*)(Ag + (long)srow * lda + scol + it * 8);
        rb[it] = *(const u16x8*)(Bg + (long)srow * ldb + scol + it * 8);
    }

    f32x4 acc[4][4] = {};

    for (int k0 = 0; k0 < Kd; k0 += 64) {
        __syncthreads();
        // ---- STAGE_WRITE: regs (k-cols k0..k0+63) -> LDS ----
#pragma unroll
        for (int it = 0; it < 4; it++) {
            *(u16x8*)&As[srow * ASTR2 + scol + it * 8] = ra[it];
            *(u16x8*)&Bs[srow * ASTR2 + scol + it * 8] = rb[it];
        }
        __syncthreads();

        // ---- STAGE_LOAD (T14): issue next 64-k tile before the MFMA phase ----
        if (k0 + 64 < Kd) {
            const int kn = k0 + 64;
#pragma unroll
            for (int it = 0; it < 4; it++) {
                ra[it] = *(const u16x8*)(Ag + (long)srow * lda + kn + scol + it * 8);
                rb[it] = *(const u16x8*)(Bg + (long)srow * ldb + kn + scol + it * 8);
            }
        }

        // ---- two k=32 sub-phases: {8 frag loads + 16 MFMA} each ----
#pragma unroll
        for (int s = 0; s < 2; s++) {
            const int kb = s * 32 + kg;
            f16x8 af[4], bfr[4];
#pragma unroll
            for (int i = 0; i < 4; i++) {
                const int r = wm + i * 16 + lr;
                af[i] = ld2h(As, r * ASTR2 + kb, r * ASTR2 + kb + 16);
            }
#pragma unroll
            for (int j = 0; j < 4; j++) {
                const int r = wn + j * 16 + lr;
                bfr[j] = ld2h(Bs, r * ASTR2 + kb, r * ASTR2 + kb + 16);
            }
#pragma unroll
            for (int i = 0; i < 4; i++)
#pragma unroll
                for (int j = 0; j < 4; j++)
                    acc[i][j] = __builtin_amdgcn_mfma_f32_16x16x32_f16(
                        af[i], bfr[j], acc[i][j], 0, 0, 0);
        }
    }

    // ---- epilogue: C/D layout col=lane&15, row=(lane>>4)*4+reg ----
    float* Cg = C + (long)blockIdx.z * sC + (long)(m0 + wm) * ldc + n0 + wn;
    const int rbase = (lane >> 4) * 4;
#pragma unroll
    for (int i = 0; i < 4; i++)
#pragma unroll
        for (int r = 0; r < 4; r++) {
            float* cp = Cg + (long)(i * 16 + rbase + r) * ldc + lr;
#pragma unroll
            for (int j = 0; j < 4; j++)
                cp[j * 16] = acc[i][j][r] * scale;
        }
}

// ===========================================================================
// Phase-1 kernel: qW = (query @ W)/32, 3-term fp16-split in, fp16 OUT.
// M=512, N=1024, K=1024, B = W^T planes [n][k]. Tile 64x64, 4 waves (32x32),
// 128 blocks; copy staging (pad-40), both operands k-contiguous.
// ===========================================================================
#define ASTR 40
__global__ __launch_bounds__(256, 2) void gemm_qw(
    const u16* __restrict__ qh, const u16* __restrict__ ql,
    const u16* __restrict__ WhT, const u16* __restrict__ WlT,
    u16* __restrict__ qWh)
{
    __shared__ u16 As[2][64 * ASTR];
    __shared__ u16 Bs[2][64 * ASTR];

    const int tid  = threadIdx.x;
    const int lane = tid & 63;
    const int wave = tid >> 6;
    const int wm = (wave >> 1) * 32, wn = (wave & 1) * 32;
    const int lr = lane & 15, kg = (lane >> 4) * 4;
    const int m0 = blockIdx.y * 64, n0 = blockIdx.x * 64;

    const u16* Ag[2] = { qh + (long)m0 * 1024, ql + (long)m0 * 1024 };
    const u16* Bg[2] = { WhT + (long)n0 * 1024, WlT + (long)n0 * 1024 };

    f32x4 acc[2][2] = {};

    for (int k0 = 0; k0 < 1024; k0 += 32) {
        __syncthreads();
        const int row = tid >> 2, kc = (tid & 3) * 8;   // 64 rows x 32 k per plane
#pragma unroll
        for (int p = 0; p < 2; p++) {
            *(u16x8*)&As[p][row * ASTR + kc] =
                *(const u16x8*)(Ag[p] + (long)row * 1024 + k0 + kc);
            *(u16x8*)&Bs[p][row * ASTR + kc] =
                *(const u16x8*)(Bg[p] + (long)row * 1024 + k0 + kc);
        }
        __syncthreads();

        f16x8 af[2][2], bfr[2][2];
#pragma unroll
        for (int i = 0; i < 2; i++) {
            const int r = wm + i * 16 + lr;
#pragma unroll
            for (int p = 0; p < 2; p++)
                af[p][i] = ld2h(&As[p][0], r * ASTR + kg, r * ASTR + kg + 16);
        }
#pragma unroll
        for (int j = 0; j < 2; j++) {
            const int r = wn + j * 16 + lr;
#pragma unroll
            for (int p = 0; p < 2; p++)
                bfr[p][j] = ld2h(&Bs[p][0], r * ASTR + kg, r * ASTR + kg + 16);
        }
#pragma unroll
        for (int i = 0; i < 2; i++)
#pragma unroll
            for (int j = 0; j < 2; j++) {
                acc[i][j] = __builtin_amdgcn_mfma_f32_16x16x32_f16(
                    af[0][i], bfr[0][j], acc[i][j], 0, 0, 0);
                acc[i][j] = __builtin_amdgcn_mfma_f32_16x16x32_f16(
                    af[0][i], bfr[1][j], acc[i][j], 0, 0, 0);
                acc[i][j] = __builtin_amdgcn_mfma_f32_16x16x32_f16(
                    af[1][i], bfr[0][j], acc[i][j], 0, 0, 0);
            }
    }

    // Epilogue: scale by 1/32, write fp16 qW.
    const int rbase = (lane >> 4) * 4;
#pragma unroll
    for (int i = 0; i < 2; i++)
#pragma unroll
        for (int r = 0; r < 4; r++) {
            const long ro = (long)(m0 + wm + i * 16 + rbase + r) * 1024 + n0 + wn + lr;
#pragma unroll
            for (int j = 0; j < 2; j++)
                qWh[ro + j * 16] = f2h(acc[i][j][r] * (1.f / 32.f));
        }
}

// ===========================================================================
// Masked softmax over rows of 2048, in place on f32 scores; optionally also
// writes an fp16 copy (phase-4 A operand). One block per row.
// ===========================================================================
__global__ __launch_bounds__(256) void softmax_rows(
    float* __restrict__ att, const int* __restrict__ mask, u16* __restrict__ ahf)
{
    const int  row  = blockIdx.x;                    // b*512 + k
    const int  tid  = threadIdx.x;
    const long base = (long)row * 2048 + tid * 8;

    f32x4 s0 = *(const f32x4*)(att + base);
    f32x4 s1 = *(const f32x4*)(att + base + 4);
    int4  mv0 = *(const int4*)(mask + base);
    int4  mv1 = *(const int4*)(mask + base + 4);
    const int mk[8] = {mv0.x, mv0.y, mv0.z, mv0.w, mv1.x, mv1.y, mv1.z, mv1.w};

    float x[8] = {s0[0], s0[1], s0[2], s0[3], s1[0], s1[1], s1[2], s1[3]};
#pragma unroll
    for (int j = 0; j < 8; j++) x[j] = mk[j] ? x[j] : -INFINITY;

    float mx = x[0];
#pragma unroll
    for (int j = 1; j < 8; j++) mx = fmaxf(mx, x[j]);
#pragma unroll
    for (int off = 32; off > 0; off >>= 1) mx = fmaxf(mx, __shfl_down(mx, off));

    __shared__ float red[8];
    const int wave = tid >> 6, lane = tid & 63;
    if (lane == 0) red[wave] = mx;
    __syncthreads();
    mx = fmaxf(fmaxf(red[0], red[1]), fmaxf(red[2], red[3]));

    if (mx == -INFINITY) {                           // all-masked row: zeros, not NaN
        f32x4 z = {0.f, 0.f, 0.f, 0.f};
        *(f32x4*)(att + base) = z;
        *(f32x4*)(att + base + 4) = z;
        if (ahf) {
            u16x8 zh = {0, 0, 0, 0, 0, 0, 0, 0};
            *(u16x8*)(ahf + base) = zh;
        }
        return;
    }

    float e[8], s = 0.f;
#pragma unroll
    for (int j = 0; j < 8; j++) { e[j] = __expf(x[j] - mx); s += e[j]; }
#pragma unroll
    for (int off = 32; off > 0; off >>= 1) s += __shfl_down(s, off);
    if (lane == 0) red[4 + wave] = s;
    __syncthreads();
    s = red[4] + red[5] + red[6] + red[7];

    const float inv = 1.f / s;
    float o[8];
#pragma unroll
    for (int j = 0; j < 8; j++) o[j] = e[j] * inv;
    f32x4 o0 = {o[0], o[1], o[2], o[3]}, o1 = {o[4], o[5], o[6], o[7]};
    *(f32x4*)(att + base) = o0;
    *(f32x4*)(att + base + 4) = o1;
    if (ahf) {
        u16x8 ph;
#pragma unroll
        for (int j = 0; j < 8; j++) ph[j] = f2h(o[j]);
        *(u16x8*)(ahf + base) = ph;
    }
}

// ===========================================================================
extern "C" void kernel_launch(void* const* d_in, const int* in_sizes, int n_in,
                              void* d_out, int out_size, void* d_ws, size_t ws_size,
                              hipStream_t stream)
{
    const float* query = nullptr;   // 512*1024      = 524288
    const float* key   = nullptr;   // 16*2048*1024  = 33554432
    const float* W     = nullptr;   // 1024*1024     = 1048576
    const int*   mask  = nullptr;   // 16*512*2048   = 16777216
    for (int i = 0; i < n_in; i++) {
        switch (in_sizes[i]) {
            case 524288:   query = (const float*)d_in[i]; break;
            case 33554432: key   = (const float*)d_in[i]; break;
            case 1048576:  W     = (const float*)d_in[i]; break;
            case 16777216: mask  = (const int*)d_in[i];   break;
        }
    }

    float* out = (float*)d_out;                     // [16,512,1024] f32
    float* att = out + (long)16 * 512 * 1024;       // [16,512,2048] f32

    const long KEY_E = 16L * 2048 * 1024;           // 33,554,432
    const long ATT_E = 16L * 512 * 2048;            // 16,777,216
    const long QW_E  = 512L * 1024;                 //    524,288
    const long W_E   = 1024L * 1024;                //  1,048,576
    // ws layout (same footprint/guard as rounds 4-8):
    //   key_h | key_hT | att_h | qW_h
    // Phase-1 scratch (q hi/lo, W hi/lo, W^T hi/lo = 5.25M u16) aliases into
    // the att_h region (16.8M u16, dead until softmax).
    const size_t WS_NEED = (size_t)(2 * KEY_E + ATT_E + 2 * QW_E) * 2;

    if (ws_size >= WS_NEED && d_ws != nullptr) {
        u16* key_h  = (u16*)d_ws;
        u16* key_hT = key_h + KEY_E;
        u16* att_h  = key_hT + KEY_E;
        u16* qW_h   = att_h + ATT_E;
        // phase-1 scratch aliased into att_h (all dead by softmax time):
        u16* q_hi   = att_h;
        u16* q_lo   = q_hi + QW_E;
        u16* W_hi   = q_lo + QW_E;
        u16* W_lo   = W_hi + W_E;
        u16* W_hiT  = W_lo + W_E;
        u16* W_loT  = W_hiT + W_E;

        // 0) key f32 -> key_h AND key_hT in ONE pass (fused transpose)
        conv_key<<<dim3(16, 32, 16), 256, 0, stream>>>(key, key_h, key_hT);
        // 0b) q/W -> fp16 hi+lo splits; transpose W planes
        split_f16<<<dim3(512),  256, 0, stream>>>(query, q_hi, q_lo, QW_E / 4);
        split_f16<<<dim3(1024), 256, 0, stream>>>(W, W_hi, W_lo, W_E / 4);
        transpose_u16<<<dim3(16, 16, 1), 256, 0, stream>>>(W_hi, W_hiT, 1024, 1024);
        transpose_u16<<<dim3(16, 16, 1), 256, 0, stream>>>(W_lo, W_loT, 1024, 1024);

        // 1) qW = (query @ W) / 32  [512 x 1024], 3-term fp16 split, fp16 out
        gemm_qw<<<dim3(16, 8, 1), 256, 0, stream>>>(
            q_hi, q_lo, W_hiT, W_loT, qW_h);

        // 2) S[b] = qW @ key[b]^T   [512 x 2048], K=1024, 1-term fp16, BK=64
        gemm_f16<<<dim3(16, 4, 16), 256, 0, stream>>>(
            qW_h, key_h, att,
            1024, 1024, 1024, 2048,
            0L, (long)2048 * 1024, (long)512 * 2048, 1.f);

        // 3) masked softmax, dual-write f32 + fp16 (overwrites q/W scratch)
        softmax_rows<<<dim3(16 * 512), 256, 0, stream>>>(att, mask, att_h);

        // 4) out[b] = att[b] @ key[b]  [512 x 1024], K=2048, 1-term fp16, BK=64
        gemm_f16<<<dim3(8, 4, 16), 256, 0, stream>>>(
            att_h, key_hT, out,
            2048, 2048, 2048, 1024,
            (long)512 * 2048, (long)1024 * 2048, (long)512 * 1024, 1.f);
    } else {
        // -------- fallback: round-1 bf16 path, no workspace --------
        float* qW = out;    // f32 scratch in out region (dead before phase 4)
        gemm_f32conv<false, true><<<dim3(8, 4, 1), 256, 0, stream>>>(
            query, W, qW, 1024, 1024, 1024, 1024, 0L, 0L, 0L, 1.f / 32.f);
        gemm_f32conv<true, true><<<dim3(16, 4, 16), 256, 0, stream>>>(
            qW, key, att, 1024, 1024, 1024, 2048,
            0L, (long)2048 * 1024, (long)512 * 2048, 1.f);
        softmax_rows<<<dim3(16 * 512), 256, 0, stream>>>(att, mask, nullptr);
        gemm_f32conv<false, false><<<dim3(8, 4, 16), 256, 0, stream>>>(
            att, key, out, 2048, 2048, 1024, 1024,
            (long)512 * 2048, (long)2048 * 1024, (long)512 * 1024, 1.f);
    }
}

// Round 10
// 450.421 us; speedup vs baseline: 1.3342x; 1.0138x over previous
//
#include <hip/hip_runtime.h>

// SimpleConcatAttention on MI355X — round 10: fix transpose-tile bank conflicts.
// Round-9 post-mortem: conv_key is the top kernel (82 µs @ 2.4 TB/s, 7.6e6
// LDS bank conflicts, VALUBusy 3%): the scatter writes T[(c+j)*72+r] put all
// 8 lane-groups on the same 4 banks (8*72 u16 = 288 dwords ≡ 0 mod 32) ->
// 8-way conflict on every scatter instruction. Fix: row-BLOCK swizzle —
// element (r,c) stored at block (r>>3) ^ sigma(c), sigma(c) = (c ^ (c>>3))&7.
// Per write instr the ^cb term walks all 8 bank-quadruples -> all 32 banks,
// 2 lanes/dword (same-address, free). Reads stay contiguous u16x8 (XOR only
// permutes 8-row blocks) at the LDS BW floor.
// Also: fuse W split+transpose into one splitT_f16 pass (3 dispatches -> 1).
// Rest identical to round 9 (BK=64 fp16 GEMMs, fused conv_key, dual softmax).

typedef float f32x4 __attribute__((ext_vector_type(4)));
typedef short s16x8 __attribute__((ext_vector_type(8)));
typedef short s16x4 __attribute__((ext_vector_type(4)));
typedef _Float16 f16x8 __attribute__((ext_vector_type(8)));
typedef unsigned short u16;
typedef unsigned short u16x8 __attribute__((ext_vector_type(8)));

// ---- conversions (compiler-visible; no inline asm per m240 lesson) ----
__device__ __forceinline__ u16 f2h(float f) {           // f32 -> fp16 RNE
    _Float16 h = (_Float16)f;
    return __builtin_bit_cast(u16, h);
}
__device__ __forceinline__ float h2f(u16 v) {           // exact expand
    return (float)__builtin_bit_cast(_Float16, v);
}
__device__ __forceinline__ u16 f2bf(float f) {          // bf16 RNE (fallback path)
    unsigned int u = __float_as_uint(f);
    return (u16)((u + 0x7fffu + ((u >> 16) & 1u)) >> 16);
}
__device__ __forceinline__ float bf2f(u16 h) {
    return __uint_as_float(((unsigned int)h) << 16);
}

// Load 8 u16 (two 8B halves) from LDS at two precomputed u16 offsets.
__device__ __forceinline__ s16x8 ld2(const u16* p, int off1, int off2) {
    s16x4 a = *(const s16x4*)(p + off1);
    s16x4 b = *(const s16x4*)(p + off2);
    s16x8 r = {a[0], a[1], a[2], a[3], b[0], b[1], b[2], b[3]};
    return r;
}
__device__ __forceinline__ f16x8 ld2h(const u16* p, int off1, int off2) {
    return __builtin_bit_cast(f16x8, ld2(p, off1, off2));
}

// Transpose-tile address (64x64 u16, col-major, stride 72): element (r, c)
// lives at col c, physical row-block (r>>3)^sigma(c), low bits r&7.
// sigma(c) = (c ^ (c>>3)) & 7 spreads scatter WRITES over all 32 banks
// (see round-10 header); reads of 8 consecutive rows stay one aligned u16x8.
__device__ __forceinline__ int tpos(int c, int rblk, int rlow) {
    const int s = (c ^ (c >> 3)) & 7;
    return c * 72 + 8 * ((rblk ^ s) & 7) + rlow;
}

// ===========================================================================
// Round-1 fused-conversion bf16 GEMM — fallback path only (ws too small).
// ===========================================================================
#define CSTR 36
typedef short bf16x8 __attribute__((ext_vector_type(8)));
__device__ __forceinline__ int swzc(int row, int k) {
    return row * CSTR + (k ^ (((row >> 2) & 7) << 2));
}
__device__ __forceinline__ bf16x8 ld_fragc(const u16* plane, int row, int kg) {
    s16x8 v = ld2(plane, swzc(row, kg), swzc(row, kg + 16));
    return __builtin_bit_cast(bf16x8, v);
}

template<bool BT, bool SPLIT>
__global__ __launch_bounds__(256, 2) void gemm_f32conv(
    const float* __restrict__ A, const float* __restrict__ B,
    float* __restrict__ C,
    int Kd, int lda, int ldb, int ldc,
    long sA, long sB, long sC, float scale)
{
    constexpr int PLANES = SPLIT ? 2 : 1;
    __shared__ u16 As[PLANES][128 * CSTR];
    __shared__ u16 Bs[PLANES][128 * CSTR];

    const int tid  = threadIdx.x;
    const int lane = tid & 63;
    const int wave = tid >> 6;
    const int wm = (wave >> 1) * 64, wn = (wave & 1) * 64;
    const int lr = lane & 15, kg = (lane >> 4) * 4;

    const int m0 = blockIdx.y * 128, n0 = blockIdx.x * 128;
    const float* Ag = A + (long)blockIdx.z * sA + (long)m0 * lda;
    const float* Bg = B + (long)blockIdx.z * sB + (BT ? (long)n0 * ldb : (long)n0);

    f32x4 acc[4][4] = {};

    for (int k0 = 0; k0 < Kd; k0 += 32) {
        __syncthreads();
#pragma unroll
        for (int it = 0; it < 4; it++) {
            const int idx = tid + it * 256;
            const int row = idx >> 3, kc = (idx & 7) * 4;
            f32x4 v = *(const f32x4*)(Ag + (long)row * lda + k0 + kc);
            ushort4 h;
            h.x = f2bf(v[0]); h.y = f2bf(v[1]); h.z = f2bf(v[2]); h.w = f2bf(v[3]);
            *(ushort4*)&As[0][swzc(row, kc)] = h;
            if constexpr (SPLIT) {
                ushort4 l;
                l.x = f2bf(v[0] - bf2f(h.x)); l.y = f2bf(v[1] - bf2f(h.y));
                l.z = f2bf(v[2] - bf2f(h.z)); l.w = f2bf(v[3] - bf2f(h.w));
                *(ushort4*)&As[1][swzc(row, kc)] = l;
            }
        }
        if constexpr (BT) {
#pragma unroll
            for (int it = 0; it < 4; it++) {
                const int idx = tid + it * 256;
                const int row = idx >> 3, kc = (idx & 7) * 4;
                f32x4 v = *(const f32x4*)(Bg + (long)row * ldb + k0 + kc);
                ushort4 h;
                h.x = f2bf(v[0]); h.y = f2bf(v[1]); h.z = f2bf(v[2]); h.w = f2bf(v[3]);
                *(ushort4*)&Bs[0][swzc(row, kc)] = h;
                if constexpr (SPLIT) {
                    ushort4 l;
                    l.x = f2bf(v[0] - bf2f(h.x)); l.y = f2bf(v[1] - bf2f(h.y));
                    l.z = f2bf(v[2] - bf2f(h.z)); l.w = f2bf(v[3] - bf2f(h.w));
                    *(ushort4*)&Bs[1][swzc(row, kc)] = l;
                }
            }
        } else {
#pragma unroll
            for (int it = 0; it < 2; it++) {
                const int idx = tid + it * 256;
                const int kk = (idx >> 5) * 2;
                const int nc = (idx & 31) * 4;
                f32x4 v0 = *(const f32x4*)(Bg + (long)(k0 + kk) * ldb + nc);
                f32x4 v1 = *(const f32x4*)(Bg + (long)(k0 + kk + 1) * ldb + nc);
#pragma unroll
                for (int e = 0; e < 4; e++) {
                    const u16 h0 = f2bf(v0[e]), h1 = f2bf(v1[e]);
                    *(unsigned*)&Bs[0][swzc(nc + e, kk)] =
                        (unsigned)h0 | ((unsigned)h1 << 16);
                    if constexpr (SPLIT) {
                        const u16 l0 = f2bf(v0[e] - bf2f(h0));
                        const u16 l1 = f2bf(v1[e] - bf2f(h1));
                        *(unsigned*)&Bs[1][swzc(nc + e, kk)] =
                            (unsigned)l0 | ((unsigned)l1 << 16);
                    }
                }
            }
        }
        __syncthreads();

        bf16x8 ah[4], bh[4], al[4], bl[4];
#pragma unroll
        for (int i = 0; i < 4; i++) {
            ah[i] = ld_fragc(&As[0][0], wm + i * 16 + lr, kg);
            if constexpr (SPLIT) al[i] = ld_fragc(&As[1][0], wm + i * 16 + lr, kg);
        }
#pragma unroll
        for (int j = 0; j < 4; j++) {
            bh[j] = ld_fragc(&Bs[0][0], wn + j * 16 + lr, kg);
            if constexpr (SPLIT) bl[j] = ld_fragc(&Bs[1][0], wn + j * 16 + lr, kg);
        }
#pragma unroll
        for (int i = 0; i < 4; i++)
#pragma unroll
            for (int j = 0; j < 4; j++) {
                acc[i][j] = __builtin_amdgcn_mfma_f32_16x16x32_bf16(
                    ah[i], bh[j], acc[i][j], 0, 0, 0);
                if constexpr (SPLIT) {
                    acc[i][j] = __builtin_amdgcn_mfma_f32_16x16x32_bf16(
                        ah[i], bl[j], acc[i][j], 0, 0, 0);
                    acc[i][j] = __builtin_amdgcn_mfma_f32_16x16x32_bf16(
                        al[i], bh[j], acc[i][j], 0, 0, 0);
                }
            }
    }

    float* Cg = C + (long)blockIdx.z * sC + (long)(m0 + wm) * ldc + n0 + wn;
    const int rbase = (lane >> 4) * 4;
#pragma unroll
    for (int i = 0; i < 4; i++)
#pragma unroll
        for (int r = 0; r < 4; r++) {
            float* cp = Cg + (long)(i * 16 + rbase + r) * ldc + lr;
#pragma unroll
            for (int j = 0; j < 4; j++)
                cp[j * 16] = acc[i][j][r] * scale;
        }
}

// ===========================================================================
// split: src f32 -> fp16 hi/lo planes (query). n4 = elems/4.
// ===========================================================================
__global__ __launch_bounds__(256) void split_f16(
    const float* __restrict__ src, u16* __restrict__ hi, u16* __restrict__ lo,
    long n4)
{
    const long stride = (long)gridDim.x * 256;
    for (long i = (long)blockIdx.x * 256 + threadIdx.x; i < n4; i += stride) {
        f32x4 v = *(const f32x4*)(src + i * 4);
        ushort4 h, l;
        h.x = f2h(v[0]); h.y = f2h(v[1]); h.z = f2h(v[2]); h.w = f2h(v[3]);
        l.x = f2h(v[0] - h2f(h.x)); l.y = f2h(v[1] - h2f(h.y));
        l.z = f2h(v[2] - h2f(h.z)); l.w = f2h(v[3] - h2f(h.w));
        *(ushort4*)(hi + i * 4) = h;
        *(ushort4*)(lo + i * 4) = l;
    }
}

// ===========================================================================
// Fused key converter: f32 key [Z][2048 n][1024 d] -> fp16 key_h (same layout)
// AND fp16 key_hT [Z][1024 d][2048 n]. Swizzled transpose tile (conflict-free
// scatter writes; see tpos).
// ===========================================================================
__global__ __launch_bounds__(256) void conv_key(
    const float* __restrict__ key, u16* __restrict__ kh, u16* __restrict__ khT)
{
    __shared__ u16 T[64 * 72];
    const int tid = threadIdx.x;
    const int d0 = blockIdx.x * 64;             // 16 blocks over d=1024
    const int n0 = blockIdx.y * 64;             // 32 blocks over n=2048
    const long zo = (long)blockIdx.z * 2048 * 1024;

    const float* src = key + zo + (long)n0 * 1024 + d0;
    u16* dh = kh + zo + (long)n0 * 1024 + d0;
#pragma unroll
    for (int it = 0; it < 2; it++) {
        const int r = it * 32 + (tid >> 3);     // n-row within tile
        const int c = (tid & 7) * 8;            // d-col within tile
        f32x4 v0 = *(const f32x4*)(src + (long)r * 1024 + c);
        f32x4 v1 = *(const f32x4*)(src + (long)r * 1024 + c + 4);
        u16 h[8];
#pragma unroll
        for (int j = 0; j < 4; j++) { h[j] = f2h(v0[j]); h[4 + j] = f2h(v1[j]); }
        u16x8 hv = {h[0], h[1], h[2], h[3], h[4], h[5], h[6], h[7]};
        *(u16x8*)(dh + (long)r * 1024 + c) = hv;          // straight fp16 write
        const int rb = r >> 3, rl = r & 7;
#pragma unroll
        for (int j = 0; j < 8; j++) T[tpos(c + j, rb, rl)] = h[j];
    }
    __syncthreads();
    u16* dt = khT + zo + (long)d0 * 2048 + n0;
#pragma unroll
    for (int it = 0; it < 2; it++) {
        const int c = it * 32 + (tid >> 3);     // d-col within tile
        const int m = tid & 7;                  // n row-block
        *(u16x8*)(dt + (long)c * 2048 + m * 8) = *(const u16x8*)&T[tpos(c, m, 0)];
    }
}

// ===========================================================================
// Fused W split+transpose: f32 W [1024 k][1024 n] -> fp16 hiT/loT [n][k].
// One read of W, both transposed planes written (replaces split + 2 transposes).
// ===========================================================================
__global__ __launch_bounds__(256) void splitT_f16(
    const float* __restrict__ src, u16* __restrict__ hiT, u16* __restrict__ loT)
{
    __shared__ u16 Th[64 * 72];
    __shared__ u16 Tl[64 * 72];
    const int tid = threadIdx.x;
    const int c0 = blockIdx.x * 64;             // n-cols
    const int r0 = blockIdx.y * 64;             // k-rows
    const float* s = src + (long)r0 * 1024 + c0;
#pragma unroll
    for (int it = 0; it < 2; it++) {
        const int r = it * 32 + (tid >> 3);     // k-row within tile
        const int c = (tid & 7) * 8;            // n-col within tile
        f32x4 v0 = *(const f32x4*)(s + (long)r * 1024 + c);
        f32x4 v1 = *(const f32x4*)(s + (long)r * 1024 + c + 4);
        const int rb = r >> 3, rl = r & 7;
#pragma unroll
        for (int j = 0; j < 8; j++) {
            const float f = (j < 4) ? v0[j] : v1[j - 4];
            const u16 h = f2h(f);
            Th[tpos(c + j, rb, rl)] = h;
            Tl[tpos(c + j, rb, rl)] = f2h(f - h2f(h));
        }
    }
    __syncthreads();
    u16* dh = hiT + (long)c0 * 1024 + r0;
    u16* dl = loT + (long)c0 * 1024 + r0;
#pragma unroll
    for (int it = 0; it < 2; it++) {
        const int c = it * 32 + (tid >> 3);     // n-col within tile
        const int m = tid & 7;                  // k row-block
        *(u16x8*)(dh + (long)c * 1024 + m * 8) = *(const u16x8*)&Th[tpos(c, m, 0)];
        *(u16x8*)(dl + (long)c * 1024 + m * 8) = *(const u16x8*)&Tl[tpos(c, m, 0)];
    }
}

// ===========================================================================
// fp16 MFMA GEMM, BK=64: both operands k-contiguous, reg-staged (pad-72) with
// T14 prefetch. 32 MFMA per staging round. Tile 128x128, 4 waves (64x64 each).
// ===========================================================================
#define ASTR2 72
__global__ __launch_bounds__(256, 3) void gemm_f16(
    const u16* __restrict__ A, const u16* __restrict__ B,
    float* __restrict__ C,
    int Kd, int lda, int ldb, int ldc,
    long sA, long sB, long sC, float scale)
{
    __shared__ u16 As[128 * ASTR2];
    __shared__ u16 Bs[128 * ASTR2];

    const int tid  = threadIdx.x;
    const int lane = tid & 63;
    const int wave = tid >> 6;
    const int wm = (wave >> 1) * 64, wn = (wave & 1) * 64;
    const int lr = lane & 15, kg = (lane >> 4) * 4;

    const int m0 = blockIdx.y * 128, n0 = blockIdx.x * 128;
    const u16* Ag = A + (long)blockIdx.z * sA + (long)m0 * lda;
    const u16* Bg = B + (long)blockIdx.z * sB + (long)n0 * ldb;

    // Per-thread staging coords: row srow (2 threads/row), 32 cols at scol.
    const int srow = tid >> 1, scol = (tid & 1) * 32;

    // Prefetch registers (static indices only — rule #20): 4 x 16B per operand.
    u16x8 ra[4], rb[4];
#pragma unroll
    for (int it = 0; it < 4; it++) {
        ra[it] = *(const u16x8*)(Ag + (long)srow * lda + scol + it * 8);
        rb[it] = *(const u16x8*)(Bg + (long)srow * ldb + scol + it * 8);
    }

    f32x4 acc[4][4] = {};

    for (int k0 = 0; k0 < Kd; k0 += 64) {
        __syncthreads();
        // ---- STAGE_WRITE: regs (k-cols k0..k0+63) -> LDS ----
#pragma unroll
        for (int it = 0; it < 4; it++) {
            *(u16x8*)&As[srow * ASTR2 + scol + it * 8] = ra[it];
            *(u16x8*)&Bs[srow * ASTR2 + scol + it * 8] = rb[it];
        }
        __syncthreads();

        // ---- STAGE_LOAD (T14): issue next 64-k tile before the MFMA phase ----
        if (k0 + 64 < Kd) {
            const int kn = k0 + 64;
#pragma unroll
            for (int it = 0; it < 4; it++) {
                ra[it] = *(const u16x8*)(Ag + (long)srow * lda + kn + scol + it * 8);
                rb[it] = *(const u16x8*)(Bg + (long)srow * ldb + kn + scol + it * 8);
            }
        }

        // ---- two k=32 sub-phases: {8 frag loads + 16 MFMA} each ----
#pragma unroll
        for (int s = 0; s < 2; s++) {
            const int kb = s * 32 + kg;
            f16x8 af[4], bfr[4];
#pragma unroll
            for (int i = 0; i < 4; i++) {
                const int r = wm + i * 16 + lr;
                af[i] = ld2h(As, r * ASTR2 + kb, r * ASTR2 + kb + 16);
            }
#pragma unroll
            for (int j = 0; j < 4; j++) {
                const int r = wn + j * 16 + lr;
                bfr[j] = ld2h(Bs, r * ASTR2 + kb, r * ASTR2 + kb + 16);
            }
#pragma unroll
            for (int i = 0; i < 4; i++)
#pragma unroll
                for (int j = 0; j < 4; j++)
                    acc[i][j] = __builtin_amdgcn_mfma_f32_16x16x32_f16(
                        af[i], bfr[j], acc[i][j], 0, 0, 0);
        }
    }

    // ---- epilogue: C/D layout col=lane&15, row=(lane>>4)*4+reg ----
    float* Cg = C + (long)blockIdx.z * sC + (long)(m0 + wm) * ldc + n0 + wn;
    const int rbase = (lane >> 4) * 4;
#pragma unroll
    for (int i = 0; i < 4; i++)
#pragma unroll
        for (int r = 0; r < 4; r++) {
            float* cp = Cg + (long)(i * 16 + rbase + r) * ldc + lr;
#pragma unroll
            for (int j = 0; j < 4; j++)
                cp[j * 16] = acc[i][j][r] * scale;
        }
}

// ===========================================================================
// Phase-1 kernel: qW = (query @ W)/32, 3-term fp16-split in, fp16 OUT.
// M=512, N=1024, K=1024, B = W^T planes [n][k]. Tile 64x64, 4 waves (32x32),
// 128 blocks; copy staging (pad-40), both operands k-contiguous.
// ===========================================================================
#define ASTR 40
__global__ __launch_bounds__(256, 2) void gemm_qw(
    const u16* __restrict__ qh, const u16* __restrict__ ql,
    const u16* __restrict__ WhT, const u16* __restrict__ WlT,
    u16* __restrict__ qWh)
{
    __shared__ u16 As[2][64 * ASTR];
    __shared__ u16 Bs[2][64 * ASTR];

    const int tid  = threadIdx.x;
    const int lane = tid & 63;
    const int wave = tid >> 6;
    const int wm = (wave >> 1) * 32, wn = (wave & 1) * 32;
    const int lr = lane & 15, kg = (lane >> 4) * 4;
    const int m0 = blockIdx.y * 64, n0 = blockIdx.x * 64;

    const u16* Ag[2] = { qh + (long)m0 * 1024, ql + (long)m0 * 1024 };
    const u16* Bg[2] = { WhT + (long)n0 * 1024, WlT + (long)n0 * 1024 };

    f32x4 acc[2][2] = {};

    for (int k0 = 0; k0 < 1024; k0 += 32) {
        __syncthreads();
        const int row = tid >> 2, kc = (tid & 3) * 8;   // 64 rows x 32 k per plane
#pragma unroll
        for (int p = 0; p < 2; p++) {
            *(u16x8*)&As[p][row * ASTR + kc] =
                *(const u16x8*)(Ag[p] + (long)row * 1024 + k0 + kc);
            *(u16x8*)&Bs[p][row * ASTR + kc] =
                *(const u16x8*)(Bg[p] + (long)row * 1024 + k0 + kc);
        }
        __syncthreads();

        f16x8 af[2][2], bfr[2][2];
#pragma unroll
        for (int i = 0; i < 2; i++) {
            const int r = wm + i * 16 + lr;
#pragma unroll
            for (int p = 0; p < 2; p++)
                af[p][i] = ld2h(&As[p][0], r * ASTR + kg, r * ASTR + kg + 16);
        }
#pragma unroll
        for (int j = 0; j < 2; j++) {
            const int r = wn + j * 16 + lr;
#pragma unroll
            for (int p = 0; p < 2; p++)
                bfr[p][j] = ld2h(&Bs[p][0], r * ASTR + kg, r * ASTR + kg + 16);
        }
#pragma unroll
        for (int i = 0; i < 2; i++)
#pragma unroll
            for (int j = 0; j < 2; j++) {
                acc[i][j] = __builtin_amdgcn_mfma_f32_16x16x32_f16(
                    af[0][i], bfr[0][j], acc[i][j], 0, 0, 0);
                acc[i][j] = __builtin_amdgcn_mfma_f32_16x16x32_f16(
                    af[0][i], bfr[1][j], acc[i][j], 0, 0, 0);
                acc[i][j] = __builtin_amdgcn_mfma_f32_16x16x32_f16(
                    af[1][i], bfr[0][j], acc[i][j], 0, 0, 0);
            }
    }

    // Epilogue: scale by 1/32, write fp16 qW.
    const int rbase = (lane >> 4) * 4;
#pragma unroll
    for (int i = 0; i < 2; i++)
#pragma unroll
        for (int r = 0; r < 4; r++) {
            const long ro = (long)(m0 + wm + i * 16 + rbase + r) * 1024 + n0 + wn + lr;
#pragma unroll
            for (int j = 0; j < 2; j++)
                qWh[ro + j * 16] = f2h(acc[i][j][r] * (1.f / 32.f));
        }
}

// ===========================================================================
// Masked softmax over rows of 2048, in place on f32 scores; optionally also
// writes an fp16 copy (phase-4 A operand). One block per row.
// ===========================================================================
__global__ __launch_bounds__(256) void softmax_rows(
    float* __restrict__ att, const int* __restrict__ mask, u16* __restrict__ ahf)
{
    const int  row  = blockIdx.x;                    // b*512 + k
    const int  tid  = threadIdx.x;
    const long base = (long)row * 2048 + tid * 8;

    f32x4 s0 = *(const f32x4*)(att + base);
    f32x4 s1 = *(const f32x4*)(att + base + 4);
    int4  mv0 = *(const int4*)(mask + base);
    int4  mv1 = *(const int4*)(mask + base + 4);
    const int mk[8] = {mv0.x, mv0.y, mv0.z, mv0.w, mv1.x, mv1.y, mv1.z, mv1.w};

    float x[8] = {s0[0], s0[1], s0[2], s0[3], s1[0], s1[1], s1[2], s1[3]};
#pragma unroll
    for (int j = 0; j < 8; j++) x[j] = mk[j] ? x[j] : -INFINITY;

    float mx = x[0];
#pragma unroll
    for (int j = 1; j < 8; j++) mx = fmaxf(mx, x[j]);
#pragma unroll
    for (int off = 32; off > 0; off >>= 1) mx = fmaxf(mx, __shfl_down(mx, off));

    __shared__ float red[8];
    const int wave = tid >> 6, lane = tid & 63;
    if (lane == 0) red[wave] = mx;
    __syncthreads();
    mx = fmaxf(fmaxf(red[0], red[1]), fmaxf(red[2], red[3]));

    if (mx == -INFINITY) {                           // all-masked row: zeros, not NaN
        f32x4 z = {0.f, 0.f, 0.f, 0.f};
        *(f32x4*)(att + base) = z;
        *(f32x4*)(att + base + 4) = z;
        if (ahf) {
            u16x8 zh = {0, 0, 0, 0, 0, 0, 0, 0};
            *(u16x8*)(ahf + base) = zh;
        }
        return;
    }

    float e[8], s = 0.f;
#pragma unroll
    for (int j = 0; j < 8; j++) { e[j] = __expf(x[j] - mx); s += e[j]; }
#pragma unroll
    for (int off = 32; off > 0; off >>= 1) s += __shfl_down(s, off);
    if (lane == 0) red[4 + wave] = s;
    __syncthreads();
    s = red[4] + red[5] + red[6] + red[7];

    const float inv = 1.f / s;
    float o[8];
#pragma unroll
    for (int j = 0; j < 8; j++) o[j] = e[j] * inv;
    f32x4 o0 = {o[0], o[1], o[2], o[3]}, o1 = {o[4], o[5], o[6], o[7]};
    *(f32x4*)(att + base) = o0;
    *(f32x4*)(att + base + 4) = o1;
    if (ahf) {
        u16x8 ph;
#pragma unroll
        for (int j = 0; j < 8; j++) ph[j] = f2h(o[j]);
        *(u16x8*)(ahf + base) = ph;
    }
}

// ===========================================================================
extern "C" void kernel_launch(void* const* d_in, const int* in_sizes, int n_in,
                              void* d_out, int out_size, void* d_ws, size_t ws_size,
                              hipStream_t stream)
{
    const float* query = nullptr;   // 512*1024      = 524288
    const float* key   = nullptr;   // 16*2048*1024  = 33554432
    const float* W     = nullptr;   // 1024*1024     = 1048576
    const int*   mask  = nullptr;   // 16*512*2048   = 16777216
    for (int i = 0; i < n_in; i++) {
        switch (in_sizes[i]) {
            case 524288:   query = (const float*)d_in[i]; break;
            case 33554432: key   = (const float*)d_in[i]; break;
            case 1048576:  W     = (const float*)d_in[i]; break;
            case 16777216: mask  = (const int*)d_in[i];   break;
        }
    }

    float* out = (float*)d_out;                     // [16,512,1024] f32
    float* att = out + (long)16 * 512 * 1024;       // [16,512,2048] f32

    const long KEY_E = 16L * 2048 * 1024;           // 33,554,432
    const long ATT_E = 16L * 512 * 2048;            // 16,777,216
    const long QW_E  = 512L * 1024;                 //    524,288
    const long W_E   = 1024L * 1024;                //  1,048,576
    // ws layout (same footprint/guard as rounds 4-9):
    //   key_h | key_hT | att_h | qW_h
    // Phase-1 scratch (q hi/lo, W^T hi/lo = 3.1M u16) aliases into the att_h
    // region (16.8M u16, dead until softmax).
    const size_t WS_NEED = (size_t)(2 * KEY_E + ATT_E + 2 * QW_E) * 2;

    if (ws_size >= WS_NEED && d_ws != nullptr) {
        u16* key_h  = (u16*)d_ws;
        u16* key_hT = key_h + KEY_E;
        u16* att_h  = key_hT + KEY_E;
        u16* qW_h   = att_h + ATT_E;
        // phase-1 scratch aliased into att_h (all dead by softmax time):
        u16* q_hi   = att_h;
        u16* q_lo   = q_hi + QW_E;
        u16* W_hiT  = q_lo + QW_E;
        u16* W_loT  = W_hiT + W_E;

        // 0) key f32 -> key_h AND key_hT in ONE pass (swizzled transpose tile)
        conv_key<<<dim3(16, 32, 16), 256, 0, stream>>>(key, key_h, key_hT);
        // 0b) q -> fp16 hi+lo; W -> transposed fp16 hi+lo in ONE pass
        split_f16<<<dim3(512), 256, 0, stream>>>(query, q_hi, q_lo, QW_E / 4);
        splitT_f16<<<dim3(16, 16, 1), 256, 0, stream>>>(W, W_hiT, W_loT);

        // 1) qW = (query @ W) / 32  [512 x 1024], 3-term fp16 split, fp16 out
        gemm_qw<<<dim3(16, 8, 1), 256, 0, stream>>>(
            q_hi, q_lo, W_hiT, W_loT, qW_h);

        // 2) S[b] = qW @ key[b]^T   [512 x 2048], K=1024, 1-term fp16, BK=64
        gemm_f16<<<dim3(16, 4, 16), 256, 0, stream>>>(
            qW_h, key_h, att,
            1024, 1024, 1024, 2048,
            0L, (long)2048 * 1024, (long)512 * 2048, 1.f);

        // 3) masked softmax, dual-write f32 + fp16 (overwrites q/W scratch)
        softmax_rows<<<dim3(16 * 512), 256, 0, stream>>>(att, mask, att_h);

        // 4) out[b] = att[b] @ key[b]  [512 x 1024], K=2048, 1-term fp16, BK=64
        gemm_f16<<<dim3(8, 4, 16), 256, 0, stream>>>(
            att_h, key_hT, out,
            2048, 2048, 2048, 1024,
            (long)512 * 2048, (long)1024 * 2048, (long)512 * 1024, 1.f);
    } else {
        // -------- fallback: round-1 bf16 path, no workspace --------
        float* qW = out;    // f32 scratch in out region (dead before phase 4)
        gemm_f32conv<false, true><<<dim3(8, 4, 1), 256, 0, stream>>>(
            query, W, qW, 1024, 1024, 1024, 1024, 0L, 0L, 0L, 1.f / 32.f);
        gemm_f32conv<true, true><<<dim3(16, 4, 16), 256, 0, stream>>>(
            qW, key, att, 1024, 1024, 1024, 2048,
            0L, (long)2048 * 1024, (long)512 * 2048, 1.f);
        softmax_rows<<<dim3(16 * 512), 256, 0, stream>>>(att, mask, nullptr);
        gemm_f32conv<false, false><<<dim3(8, 4, 16), 256, 0, stream>>>(
            att, key, out, 2048, 2048, 1024, 1024,
            (long)512 * 2048, (long)2048 * 1024, (long)512 * 1024, 1.f);
    }
}